// Round 1
// baseline (495.884 us; speedup 1.0000x reference)
//
#include <hip/hip_runtime.h>

#define BB 2
#define SS 2048
#define DD 512
#define HH 8
#define DKK 64
#define NROWS (BB * SS)          // 4096
#define Y_SIZE (BB * SS * DD)    // 2097152

typedef __attribute__((ext_vector_type(8))) short short8;
typedef __attribute__((ext_vector_type(4))) float f32x4;

__device__ __forceinline__ ushort f2bf(float f) {
  union { float f; unsigned u; } v; v.f = f;
  unsigned u = v.u;
  return (ushort)((u + 0x7fffu + ((u >> 16) & 1u)) >> 16);
}

// ---------------- converts ----------------

__global__ __launch_bounds__(256) void conv_x_kernel(const float* __restrict__ x,
                                                     ushort* __restrict__ xb) {
  int i = (blockIdx.x * 256 + threadIdx.x) * 4;
  float4 v = *(const float4*)(x + i);
  ushort4 o = {f2bf(v.x), f2bf(v.y), f2bf(v.z), f2bf(v.w)};
  *(ushort4*)(xb + i) = o;
}

// transpose 512x512 fp32 w[k][n] -> bf16 wt[n][k]
__global__ __launch_bounds__(256) void conv_wt_kernel(
    const float* __restrict__ w0, const float* __restrict__ w1,
    const float* __restrict__ w2, const float* __restrict__ w3,
    ushort* __restrict__ o0, ushort* __restrict__ o1,
    ushort* __restrict__ o2, ushort* __restrict__ o3) {
  __shared__ float T[64][65];
  const float* w; ushort* wt;
  switch (blockIdx.z) {
    case 0: w = w0; wt = o0; break;
    case 1: w = w1; wt = o1; break;
    case 2: w = w2; wt = o2; break;
    default: w = w3; wt = o3; break;
  }
  const int t = threadIdx.x;
  const int n0 = blockIdx.x * 64, k0 = blockIdx.y * 64;
#pragma unroll
  for (int i = 0; i < 4; ++i) {
    int c = t + i * 256;
    int row = c >> 4, cc = c & 15;
    float4 v = *(const float4*)(w + (size_t)(k0 + row) * DD + n0 + cc * 4);
    T[row][cc * 4 + 0] = v.x; T[row][cc * 4 + 1] = v.y;
    T[row][cc * 4 + 2] = v.z; T[row][cc * 4 + 3] = v.w;
  }
  __syncthreads();
#pragma unroll
  for (int i = 0; i < 2; ++i) {
    int c = t + i * 256;
    int nr = c >> 3, kc = c & 7;
    ushort4 a, b;
    a.x = f2bf(T[kc * 8 + 0][nr]); a.y = f2bf(T[kc * 8 + 1][nr]);
    a.z = f2bf(T[kc * 8 + 2][nr]); a.w = f2bf(T[kc * 8 + 3][nr]);
    b.x = f2bf(T[kc * 8 + 4][nr]); b.y = f2bf(T[kc * 8 + 5][nr]);
    b.z = f2bf(T[kc * 8 + 6][nr]); b.w = f2bf(T[kc * 8 + 7][nr]);
    *(ushort4*)(wt + (size_t)(n0 + nr) * DD + k0 + kc * 8) = a;
    *(ushort4*)(wt + (size_t)(n0 + nr) * DD + k0 + kc * 8 + 4) = b;
  }
}

// ---------------- shared MFMA GEMM body: 64x64 tile, BK=64, NT form ----------
// A rows [m][k] k-contig, B rows [n][k] k-contig, both bf16(ushort).

__device__ __forceinline__ void mfma_gemm64(
    const ushort* __restrict__ A, int lda, const ushort* __restrict__ B, int ldb,
    int K, ushort (*As)[72], ushort (*Bs)[72], f32x4 (&acc)[2][2], int t) {
  const int l = t & 63, w = t >> 6;
  const int mq = w & 1, nq = w >> 1;
  const int l15 = l & 15, l4 = l >> 4;
  for (int k0 = 0; k0 < K; k0 += 64) {
    __syncthreads();
#pragma unroll
    for (int i = 0; i < 2; ++i) {
      int c = t + i * 256;
      int row = c >> 3, cc = c & 7;
      *(uint4*)&As[row][cc * 8] = *(const uint4*)(A + (size_t)row * lda + k0 + cc * 8);
      *(uint4*)&Bs[row][cc * 8] = *(const uint4*)(B + (size_t)row * ldb + k0 + cc * 8);
    }
    __syncthreads();
    short8 af[2][2], bf[2][2];
#pragma unroll
    for (int mt = 0; mt < 2; ++mt)
#pragma unroll
      for (int ks = 0; ks < 2; ++ks)
        af[mt][ks] = *(const short8*)&As[32 * mq + 16 * mt + l15][ks * 32 + l4 * 8];
#pragma unroll
    for (int nt = 0; nt < 2; ++nt)
#pragma unroll
      for (int ks = 0; ks < 2; ++ks)
        bf[nt][ks] = *(const short8*)&Bs[32 * nq + 16 * nt + l15][ks * 32 + l4 * 8];
#pragma unroll
    for (int mt = 0; mt < 2; ++mt)
#pragma unroll
      for (int nt = 0; nt < 2; ++nt)
#pragma unroll
        for (int ks = 0; ks < 2; ++ks)
          acc[mt][nt] = __builtin_amdgcn_mfma_f32_16x16x32_bf16(
              af[mt][ks], bf[nt][ks], acc[mt][nt], 0, 0, 0);
  }
}

// ---------------- QKV projection ----------------
// out: q,k as bf16 [z][s][dk]; v transposed bf16 [z][dk][s]

__global__ __launch_bounds__(256) void proj_qkv_kernel(
    const ushort* __restrict__ xb,
    const ushort* __restrict__ wqt, const float* __restrict__ bq,
    const ushort* __restrict__ wkt, const float* __restrict__ bk,
    const ushort* __restrict__ wvt, const float* __restrict__ bv,
    ushort* __restrict__ qb, ushort* __restrict__ kb, ushort* __restrict__ vt) {
  __shared__ ushort As[64][72], Bs[64][72];
  const ushort* W; const float* bias; ushort* out;
  if (blockIdx.z == 0) { W = wqt; bias = bq; out = qb; }
  else if (blockIdx.z == 1) { W = wkt; bias = bk; out = kb; }
  else { W = wvt; bias = bv; out = vt; }
  const int m0 = blockIdx.x * 64;
  const int h = blockIdx.y;
  const int t = threadIdx.x;
  const int l = t & 63, w = t >> 6;
  const int mq = w & 1, nq = w >> 1;
  const int l15 = l & 15, l4 = l >> 4;
  f32x4 acc[2][2] = {};
  mfma_gemm64(xb + (size_t)m0 * DD, DD, W + (size_t)h * DKK * DD, DD, DD,
              As, Bs, acc, t);
  float biasv[2];
#pragma unroll
  for (int nt = 0; nt < 2; ++nt) biasv[nt] = bias[h * DKK + 32 * nq + 16 * nt + l15];

  if (blockIdx.z < 2) {
    // bounce via LDS, store [z][s][dk] coalesced
    __syncthreads();
#pragma unroll
    for (int mt = 0; mt < 2; ++mt)
#pragma unroll
      for (int nt = 0; nt < 2; ++nt)
#pragma unroll
        for (int r = 0; r < 4; ++r)
          As[32 * mq + 16 * mt + l4 * 4 + r][32 * nq + 16 * nt + l15] =
              f2bf(acc[mt][nt][r] + biasv[nt]);
    __syncthreads();
#pragma unroll
    for (int i = 0; i < 2; ++i) {
      int c = t + i * 256;
      int row = c >> 3, cc = c & 7;
      int m = m0 + row, b = m >> 11, s = m & (SS - 1);
      uint4 v = *(const uint4*)&As[row][cc * 8];
      *(uint4*)(out + ((size_t)(b * HH + h) * SS + s) * DKK + cc * 8) = v;
    }
  } else {
    // v: direct transposed store [z][dk][s]
#pragma unroll
    for (int mt = 0; mt < 2; ++mt)
#pragma unroll
      for (int nt = 0; nt < 2; ++nt) {
        int dk = 32 * nq + 16 * nt + l15;
        int m = m0 + 32 * mq + 16 * mt + l4 * 4;
        int b = m >> 11, sb = m & (SS - 1);
        ushort4 pk;
        pk.x = f2bf(acc[mt][nt][0] + biasv[nt]);
        pk.y = f2bf(acc[mt][nt][1] + biasv[nt]);
        pk.z = f2bf(acc[mt][nt][2] + biasv[nt]);
        pk.w = f2bf(acc[mt][nt][3] + biasv[nt]);
        *(ushort4*)(out + ((size_t)(b * HH + h) * DKK + dk) * SS + sb) = pk;
      }
  }
}

// ---------------- fused attention: scores + softmax + AV ----------------
// 512 threads (8 waves), 64 q-rows x 128 k-cols per iteration, 16 iters/pass.
// Raw s_barrier + lgkmcnt-only waits: attn stores & prefetch loads stay in
// flight across barriers (no vmcnt(0) drains in the loop).
// grid (z=16, qt=32): flattened bid % 8 == z % 8 -> 2 z-slices per XCD,
// K+V working set 1 MB/XCD (L2-resident).

#define LGKM0() do { asm volatile("s_waitcnt lgkmcnt(0)" ::: "memory"); \
                     __builtin_amdgcn_sched_barrier(0); } while (0)
#define BARRIER() do { __builtin_amdgcn_sched_barrier(0); \
                       __builtin_amdgcn_s_barrier(); \
                       __builtin_amdgcn_sched_barrier(0); } while (0)

__global__ __launch_bounds__(512, 2) void attn_kernel(
    const ushort* __restrict__ qb, const ushort* __restrict__ kb,
    const ushort* __restrict__ vt, float* __restrict__ attn,
    ushort* __restrict__ ctx) {
  __shared__ __align__(16) ushort Ks[128][72];   // K tile: 128 s x 64 dk
  __shared__ __align__(16) ushort Vs[64][136];   // V tile: 64 dk x 128 s
  __shared__ __align__(16) ushort Ps[64][136];   // P tile: 64 q x 128 k
  __shared__ float rs[64];
  const int t = threadIdx.x;
  const int l = t & 63, w = t >> 6;
  const int mq = w & 1, nq = w >> 1;             // 2 m-halves x 4 n-quads
  const int l15 = l & 15, l4 = l >> 4;
  const int z = blockIdx.x;
  const int q0 = blockIdx.y * 64;
  if (t < 64) rs[t] = 0.f;

  // Q fragments in registers for the whole kernel
  short8 qf[2][2];
#pragma unroll
  for (int mt = 0; mt < 2; ++mt)
#pragma unroll
    for (int ks = 0; ks < 2; ++ks)
      qf[mt][ks] = *(const short8*)(qb +
          ((size_t)z * SS + q0 + 32 * mq + 16 * mt + l15) * DKK + ks * 32 + l4 * 8);

  float rowf[2][4]; int qi_[2][4];
#pragma unroll
  for (int mt = 0; mt < 2; ++mt)
#pragma unroll
    for (int r = 0; r < 4; ++r) {
      int qi = q0 + 32 * mq + 16 * mt + l4 * 4 + r;
      qi_[mt][r] = qi;
      rowf[mt][r] = __expf(-0.02f * (float)qi);
    }

  // staging: prefetch next tile into registers, ds_write after read barrier
  uint4 kr[2], vr[2];
  const int krow = t >> 3, kcol = (t & 7) * 8;   // 128 rows x 64, 2 uint4/thread
  const int krow2 = krow + 64;
  const int vrow = t >> 4, vcol = (t & 15) * 8;  // 64 rows x 128, 2 uint4/thread
  const int vrow2 = vrow + 32;

  auto kload = [&](int kt2) {
    const ushort* p = kb + ((size_t)z * SS + (size_t)kt2 * 128) * DKK;
    kr[0] = *(const uint4*)(p + (size_t)krow * DKK + kcol);
    kr[1] = *(const uint4*)(p + (size_t)krow2 * DKK + kcol);
  };
  auto vload = [&](int kt2) {
    const ushort* p = vt + (size_t)z * DKK * SS + kt2 * 128;
    vr[0] = *(const uint4*)(p + (size_t)vrow * SS + vcol);
    vr[1] = *(const uint4*)(p + (size_t)vrow2 * SS + vcol);
  };
  auto kwrite = [&]() {
    *(uint4*)&Ks[krow][kcol] = kr[0];
    *(uint4*)&Ks[krow2][kcol] = kr[1];
  };
  auto vwrite = [&]() {
    *(uint4*)&Vs[vrow][vcol] = vr[0];
    *(uint4*)&Vs[vrow2][vcol] = vr[1];
  };

  // ---- pass 1: row sums of exp(score) ----
  kload(0);
  kwrite();
  LGKM0(); BARRIER();

  float rsp[2][4] = {};
  for (int kt = 0; kt < 16; ++kt) {
    if (kt < 15) kload(kt + 1);
    short8 bfr[2][2];
#pragma unroll
    for (int nt = 0; nt < 2; ++nt)
#pragma unroll
      for (int ks = 0; ks < 2; ++ks)
        bfr[nt][ks] = *(const short8*)&Ks[32 * nq + 16 * nt + l15][ks * 32 + l4 * 8];
    f32x4 acc[2][2] = {};
    __builtin_amdgcn_s_setprio(1);
#pragma unroll
    for (int mt = 0; mt < 2; ++mt)
#pragma unroll
      for (int nt = 0; nt < 2; ++nt)
#pragma unroll
        for (int ks = 0; ks < 2; ++ks)
          acc[mt][nt] = __builtin_amdgcn_mfma_f32_16x16x32_bf16(
              qf[mt][ks], bfr[nt][ks], acc[mt][nt], 0, 0, 0);
    __builtin_amdgcn_s_setprio(0);
#pragma unroll
    for (int nt = 0; nt < 2; ++nt) {
      int kj = kt * 128 + 32 * nq + 16 * nt + l15;
      float colf = __expf(0.02f * (float)kj);
#pragma unroll
      for (int mt = 0; mt < 2; ++mt)
#pragma unroll
        for (int r = 0; r < 4; ++r) {
          float bias = (kj <= qi_[mt][r]) ? rowf[mt][r] * colf : 0.f;
          rsp[mt][r] += __expf(fmaf(acc[mt][nt][r], 0.125f, bias));
        }
    }
    BARRIER();                          // all waves' Ks reads consumed
    if (kt < 15) { kwrite(); LGKM0(); BARRIER(); }
  }

  // prefetch pass-2 tile 0 while reducing row sums
  kload(0); vload(0);

#pragma unroll
  for (int mt = 0; mt < 2; ++mt)
#pragma unroll
    for (int r = 0; r < 4; ++r) {
      float v = rsp[mt][r];
      v += __shfl_xor(v, 1); v += __shfl_xor(v, 2);
      v += __shfl_xor(v, 4); v += __shfl_xor(v, 8);
      if (l15 == 0) atomicAdd(&rs[32 * mq + 16 * mt + l4 * 4 + r], v);
    }
  __syncthreads();
  float inv[2][4];
#pragma unroll
  for (int mt = 0; mt < 2; ++mt)
#pragma unroll
    for (int r = 0; r < 4; ++r)
      inv[mt][r] = 1.f / rs[32 * mq + 16 * mt + l4 * 4 + r];
  kwrite(); vwrite();
  LGKM0(); BARRIER();

  // ---- pass 2: recompute, normalize, write attn, accumulate PV ----
  f32x4 oacc[2] = {};                   // 32 q x 16 dk per wave
  for (int kt = 0; kt < 16; ++kt) {
    if (kt < 15) { kload(kt + 1); vload(kt + 1); }
    short8 bfr[2][2];
#pragma unroll
    for (int nt = 0; nt < 2; ++nt)
#pragma unroll
      for (int ks = 0; ks < 2; ++ks)
        bfr[nt][ks] = *(const short8*)&Ks[32 * nq + 16 * nt + l15][ks * 32 + l4 * 8];
    f32x4 acc[2][2] = {};
    __builtin_amdgcn_s_setprio(1);
#pragma unroll
    for (int mt = 0; mt < 2; ++mt)
#pragma unroll
      for (int nt = 0; nt < 2; ++nt)
#pragma unroll
        for (int ks = 0; ks < 2; ++ks)
          acc[mt][nt] = __builtin_amdgcn_mfma_f32_16x16x32_bf16(
              qf[mt][ks], bfr[nt][ks], acc[mt][nt], 0, 0, 0);
    __builtin_amdgcn_s_setprio(0);
#pragma unroll
    for (int nt = 0; nt < 2; ++nt) {
      int kj = kt * 128 + 32 * nq + 16 * nt + l15;
      float colf = __expf(0.02f * (float)kj);
#pragma unroll
      for (int mt = 0; mt < 2; ++mt)
#pragma unroll
        for (int r = 0; r < 4; ++r) {
          float bias = (kj <= qi_[mt][r]) ? rowf[mt][r] * colf : 0.f;
          float p = __expf(fmaf(acc[mt][nt][r], 0.125f, bias)) * inv[mt][r];
          attn[((size_t)z * SS + qi_[mt][r]) * SS + kj] = p;
          Ps[32 * mq + 16 * mt + l4 * 4 + r][32 * nq + 16 * nt + l15] = f2bf(p);
        }
    }
    LGKM0(); BARRIER();                 // P tile visible to all waves
    __builtin_amdgcn_s_setprio(1);
#pragma unroll
    for (int ks = 0; ks < 4; ++ks) {
      short8 pb = *(const short8*)&Vs[16 * nq + l15][ks * 32 + l4 * 8];
#pragma unroll
      for (int mt = 0; mt < 2; ++mt) {
        short8 pa = *(const short8*)&Ps[32 * mq + 16 * mt + l15][ks * 32 + l4 * 8];
        oacc[mt] = __builtin_amdgcn_mfma_f32_16x16x32_bf16(pa, pb, oacc[mt], 0, 0, 0);
      }
    }
    __builtin_amdgcn_s_setprio(0);
    BARRIER();                          // all Vs/Ps reads consumed
    if (kt < 15) { kwrite(); vwrite(); LGKM0(); BARRIER(); }
  }

  // epilogue: ctx tile (bf16 [4096][512]) via LDS bounce
#pragma unroll
  for (int mt = 0; mt < 2; ++mt)
#pragma unroll
    for (int r = 0; r < 4; ++r)
      Ps[32 * mq + 16 * mt + l4 * 4 + r][16 * nq + l15] = f2bf(oacc[mt][r]);
  LGKM0(); BARRIER();
  {
    const int b = z >> 3, h = z & 7;
    const int row = t >> 3, cc = t & 7;
    *(uint4*)(ctx + ((size_t)(b * SS + q0 + row)) * DD + h * DKK + cc * 8) =
        *(const uint4*)&Ps[row][cc * 8];
  }
}

// ---------------- O projection ----------------

__global__ __launch_bounds__(256) void proj_o_kernel(
    const ushort* __restrict__ ctx, const ushort* __restrict__ wot,
    const float* __restrict__ bo, float* __restrict__ o) {
  __shared__ ushort As[64][72], Bs[64][72];
  const int m0 = blockIdx.x * 64, n0 = blockIdx.y * 64;
  const int t = threadIdx.x;
  const int l = t & 63, w = t >> 6;
  const int mq = w & 1, nq = w >> 1;
  const int l15 = l & 15, l4 = l >> 4;
  f32x4 acc[2][2] = {};
  mfma_gemm64(ctx + (size_t)m0 * DD, DD, wot + (size_t)n0 * DD, DD, DD,
              As, Bs, acc, t);
#pragma unroll
  for (int nt = 0; nt < 2; ++nt) {
    int col = n0 + 32 * nq + 16 * nt + l15;
    float bv = bo[col];
#pragma unroll
    for (int mt = 0; mt < 2; ++mt)
#pragma unroll
      for (int r = 0; r < 4; ++r) {
        int m = m0 + 32 * mq + 16 * mt + l4 * 4 + r;
        o[(size_t)m * DD + col] = acc[mt][nt][r] + bv;
      }
  }
}

// ---------------- gate MLP (fp32, small) ----------------

__global__ __launch_bounds__(256) void gate_kernel(
    const float* __restrict__ x, const float* __restrict__ g1w,
    const float* __restrict__ g1b, const float* __restrict__ g2w,
    const float* __restrict__ g2b, float* __restrict__ gate) {
  __shared__ float xs[8][512];
  __shared__ float red[32];
  const int r0 = blockIdx.x * 8;
  const int t = threadIdx.x;
  const float4* xg = (const float4*)&x[(size_t)r0 * DD];
  float4* xsv = (float4*)&xs[0][0];
#pragma unroll
  for (int i = 0; i < 4; ++i) xsv[t + i * 256] = xg[t + i * 256];
  __syncthreads();
  float acc[8] = {};
  for (int i = 0; i < 512; i += 4) {
    float w0 = g1w[(i + 0) * 256 + t];
    float w1 = g1w[(i + 1) * 256 + t];
    float w2 = g1w[(i + 2) * 256 + t];
    float w3 = g1w[(i + 3) * 256 + t];
#pragma unroll
    for (int r = 0; r < 8; ++r) {
      float4 xv = *(const float4*)&xs[r][i];
      acc[r] += xv.x * w0 + xv.y * w1 + xv.z * w2 + xv.w * w3;
    }
  }
  float b1 = g1b[t], w2_ = g2w[t];
  float p[8];
#pragma unroll
  for (int r = 0; r < 8; ++r) {
    float h = acc[r] + b1;
    h = h > 0.f ? h : 0.f;
    p[r] = h * w2_;
  }
#pragma unroll
  for (int r = 0; r < 8; ++r)
    for (int off = 32; off; off >>= 1) p[r] += __shfl_xor(p[r], off, 64);
  if ((t & 63) == 0) {
#pragma unroll
    for (int r = 0; r < 8; ++r) red[r * 4 + (t >> 6)] = p[r];
  }
  __syncthreads();
  if (t < 8) {
    float s = red[t * 4] + red[t * 4 + 1] + red[t * 4 + 2] + red[t * 4 + 3] + g2b[0];
    gate[r0 + t] = 1.f / (1.f + __expf(-s));
  }
}

// ---------------- gated blend + layernorm ----------------

__global__ __launch_bounds__(256) void blend_ln_kernel(
    const float* __restrict__ o, const float* __restrict__ x,
    const float* __restrict__ gate, const float* __restrict__ ln_g,
    const float* __restrict__ ln_b, float* __restrict__ y) {
  __shared__ float r1[4], r2[4];
  const int row = blockIdx.x, t = threadIdx.x;
  float g = gate[row];
  float2 o2 = *(const float2*)&o[(size_t)row * DD + t * 2];
  float2 x2 = *(const float2*)&x[(size_t)row * DD + t * 2];
  float va = o2.x * g + x2.x * (1.f - g);
  float vb = o2.y * g + x2.y * (1.f - g);
  float s = va + vb, q = va * va + vb * vb;
  for (int off = 32; off; off >>= 1) {
    s += __shfl_xor(s, off, 64);
    q += __shfl_xor(q, off, 64);
  }
  if ((t & 63) == 0) { r1[t >> 6] = s; r2[t >> 6] = q; }
  __syncthreads();
  s = r1[0] + r1[1] + r1[2] + r1[3];
  q = r2[0] + r2[1] + r2[2] + r2[3];
  float mean = s * (1.f / 512.f);
  float var = q * (1.f / 512.f) - mean * mean;
  float rstd = rsqrtf(var + 1e-5f);
  float2 lg = *(const float2*)&ln_g[t * 2];
  float2 lb = *(const float2*)&ln_b[t * 2];
  float2 out;
  out.x = (va - mean) * rstd * lg.x + lb.x;
  out.y = (vb - mean) * rstd * lg.y + lb.y;
  *(float2*)&y[(size_t)row * DD + t * 2] = out;
}

extern "C" void kernel_launch(void* const* d_in, const int* in_sizes, int n_in,
                              void* d_out, int out_size, void* d_ws, size_t ws_size,
                              hipStream_t stream) {
  const float* x   = (const float*)d_in[0];
  const float* wq  = (const float*)d_in[1];
  const float* bq  = (const float*)d_in[2];
  const float* wk  = (const float*)d_in[3];
  const float* bk  = (const float*)d_in[4];
  const float* wv  = (const float*)d_in[5];
  const float* bv  = (const float*)d_in[6];
  const float* wo  = (const float*)d_in[7];
  const float* bo  = (const float*)d_in[8];
  const float* g1w = (const float*)d_in[9];
  const float* g1b = (const float*)d_in[10];
  const float* g2w = (const float*)d_in[11];
  const float* g2b = (const float*)d_in[12];
  const float* lng = (const float*)d_in[13];
  const float* lnb = (const float*)d_in[14];

  float* y    = (float*)d_out;
  float* attn = y + (size_t)Y_SIZE;

  char* ws = (char*)d_ws;
  ushort* xb  = (ushort*)(ws);                       // 4 MB
  ushort* wqt = (ushort*)(ws + (4 << 20));           // 512 KB
  ushort* wkt = (ushort*)(ws + (4 << 20) + (512 << 10));
  ushort* wvt = (ushort*)(ws + (5 << 20));
  ushort* wot = (ushort*)(ws + (5 << 20) + (512 << 10));
  ushort* qb  = (ushort*)(ws + (6 << 20));           // 4 MB
  ushort* kb  = (ushort*)(ws + (10 << 20));          // 4 MB
  ushort* vt  = (ushort*)(ws + (14 << 20));          // 4 MB
  ushort* ctx = (ushort*)(ws + (18 << 20));          // 4 MB
  float*  o   = (float*)(ws + (22 << 20));           // 8 MB
  float*  gate= (float*)(ws + (30 << 20));           // 16 KB

  hipLaunchKernelGGL(conv_x_kernel, dim3(Y_SIZE / 1024), dim3(256), 0, stream, x, xb);
  hipLaunchKernelGGL(conv_wt_kernel, dim3(8, 8, 4), dim3(256), 0, stream,
                     wq, wk, wv, wo, wqt, wkt, wvt, wot);
  hipLaunchKernelGGL(proj_qkv_kernel, dim3(64, 8, 3), dim3(256), 0, stream,
                     xb, wqt, bq, wkt, bk, wvt, bv, qb, kb, vt);
  hipLaunchKernelGGL(gate_kernel, dim3(512), dim3(256), 0, stream,
                     x, g1w, g1b, g2w, g2b, gate);
  hipLaunchKernelGGL(attn_kernel, dim3(16, 32), dim3(512), 0, stream,
                     qb, kb, vt, attn, ctx);
  hipLaunchKernelGGL(proj_o_kernel, dim3(64, 8), dim3(256), 0, stream,
                     ctx, wot, bo, o);
  hipLaunchKernelGGL(blend_ln_kernel, dim3(4096), dim3(256), 0, stream,
                     o, x, gate, lng, lnb, y);
}

// Round 2
// 484.660 us; speedup vs baseline: 1.0232x; 1.0232x over previous
//
#include <hip/hip_runtime.h>

#define BB 2
#define SS 2048
#define DD 512
#define HH 8
#define DKK 64
#define NROWS (BB * SS)          // 4096
#define Y_SIZE (BB * SS * DD)    // 2097152

typedef __attribute__((ext_vector_type(8))) short short8;
typedef __attribute__((ext_vector_type(4))) float f32x4;

__device__ __forceinline__ ushort f2bf(float f) {
  union { float f; unsigned u; } v; v.f = f;
  unsigned u = v.u;
  return (ushort)((u + 0x7fffu + ((u >> 16) & 1u)) >> 16);
}

__device__ __forceinline__ float bf2f(ushort u) {
  union { unsigned u; float f; } v; v.u = ((unsigned)u) << 16;
  return v.f;
}

// ---------------- converts ----------------

__global__ __launch_bounds__(256) void conv_x_kernel(const float* __restrict__ x,
                                                     ushort* __restrict__ xb) {
  int i = (blockIdx.x * 256 + threadIdx.x) * 4;
  float4 v = *(const float4*)(x + i);
  ushort4 o = {f2bf(v.x), f2bf(v.y), f2bf(v.z), f2bf(v.w)};
  *(ushort4*)(xb + i) = o;
}

// transpose 512x512 fp32 w[k][n] -> bf16 wt[n][k]
__global__ __launch_bounds__(256) void conv_wt_kernel(
    const float* __restrict__ w0, const float* __restrict__ w1,
    const float* __restrict__ w2, const float* __restrict__ w3,
    ushort* __restrict__ o0, ushort* __restrict__ o1,
    ushort* __restrict__ o2, ushort* __restrict__ o3) {
  __shared__ float T[64][65];
  const float* w; ushort* wt;
  switch (blockIdx.z) {
    case 0: w = w0; wt = o0; break;
    case 1: w = w1; wt = o1; break;
    case 2: w = w2; wt = o2; break;
    default: w = w3; wt = o3; break;
  }
  const int t = threadIdx.x;
  const int n0 = blockIdx.x * 64, k0 = blockIdx.y * 64;
#pragma unroll
  for (int i = 0; i < 4; ++i) {
    int c = t + i * 256;
    int row = c >> 4, cc = c & 15;
    float4 v = *(const float4*)(w + (size_t)(k0 + row) * DD + n0 + cc * 4);
    T[row][cc * 4 + 0] = v.x; T[row][cc * 4 + 1] = v.y;
    T[row][cc * 4 + 2] = v.z; T[row][cc * 4 + 3] = v.w;
  }
  __syncthreads();
#pragma unroll
  for (int i = 0; i < 2; ++i) {
    int c = t + i * 256;
    int nr = c >> 3, kc = c & 7;
    ushort4 a, b;
    a.x = f2bf(T[kc * 8 + 0][nr]); a.y = f2bf(T[kc * 8 + 1][nr]);
    a.z = f2bf(T[kc * 8 + 2][nr]); a.w = f2bf(T[kc * 8 + 3][nr]);
    b.x = f2bf(T[kc * 8 + 4][nr]); b.y = f2bf(T[kc * 8 + 5][nr]);
    b.z = f2bf(T[kc * 8 + 6][nr]); b.w = f2bf(T[kc * 8 + 7][nr]);
    *(ushort4*)(wt + (size_t)(n0 + nr) * DD + k0 + kc * 8) = a;
    *(ushort4*)(wt + (size_t)(n0 + nr) * DD + k0 + kc * 8 + 4) = b;
  }
}

// ---------------- shared MFMA GEMM body: 64x64 tile, BK=64, NT form ----------

__device__ __forceinline__ void mfma_gemm64(
    const ushort* __restrict__ A, int lda, const ushort* __restrict__ B, int ldb,
    int K, ushort (*As)[72], ushort (*Bs)[72], f32x4 (&acc)[2][2], int t) {
  const int l = t & 63, w = t >> 6;
  const int mq = w & 1, nq = w >> 1;
  const int l15 = l & 15, l4 = l >> 4;
  for (int k0 = 0; k0 < K; k0 += 64) {
    __syncthreads();
#pragma unroll
    for (int i = 0; i < 2; ++i) {
      int c = t + i * 256;
      int row = c >> 3, cc = c & 7;
      *(uint4*)&As[row][cc * 8] = *(const uint4*)(A + (size_t)row * lda + k0 + cc * 8);
      *(uint4*)&Bs[row][cc * 8] = *(const uint4*)(B + (size_t)row * ldb + k0 + cc * 8);
    }
    __syncthreads();
    short8 af[2][2], bf[2][2];
#pragma unroll
    for (int mt = 0; mt < 2; ++mt)
#pragma unroll
      for (int ks = 0; ks < 2; ++ks)
        af[mt][ks] = *(const short8*)&As[32 * mq + 16 * mt + l15][ks * 32 + l4 * 8];
#pragma unroll
    for (int nt = 0; nt < 2; ++nt)
#pragma unroll
      for (int ks = 0; ks < 2; ++ks)
        bf[nt][ks] = *(const short8*)&Bs[32 * nq + 16 * nt + l15][ks * 32 + l4 * 8];
#pragma unroll
    for (int mt = 0; mt < 2; ++mt)
#pragma unroll
      for (int nt = 0; nt < 2; ++nt)
#pragma unroll
        for (int ks = 0; ks < 2; ++ks)
          acc[mt][nt] = __builtin_amdgcn_mfma_f32_16x16x32_bf16(
              af[mt][ks], bf[nt][ks], acc[mt][nt], 0, 0, 0);
  }
}

// ---------------- QKV projection ----------------
// out: q (prescaled by 1/8), k as bf16 [z][s][dk]; v transposed bf16 [z][dk][s]

__global__ __launch_bounds__(256) void proj_qkv_kernel(
    const ushort* __restrict__ xb,
    const ushort* __restrict__ wqt, const float* __restrict__ bq,
    const ushort* __restrict__ wkt, const float* __restrict__ bk,
    const ushort* __restrict__ wvt, const float* __restrict__ bv,
    ushort* __restrict__ qb, ushort* __restrict__ kb, ushort* __restrict__ vt) {
  __shared__ ushort As[64][72], Bs[64][72];
  const ushort* W; const float* bias; ushort* out;
  if (blockIdx.z == 0) { W = wqt; bias = bq; out = qb; }
  else if (blockIdx.z == 1) { W = wkt; bias = bk; out = kb; }
  else { W = wvt; bias = bv; out = vt; }
  const float scale = (blockIdx.z == 0) ? 0.125f : 1.0f;  // fold 1/sqrt(dk) into Q
  const int m0 = blockIdx.x * 64;
  const int h = blockIdx.y;
  const int t = threadIdx.x;
  const int l = t & 63, w = t >> 6;
  const int mq = w & 1, nq = w >> 1;
  const int l15 = l & 15, l4 = l >> 4;
  f32x4 acc[2][2] = {};
  mfma_gemm64(xb + (size_t)m0 * DD, DD, W + (size_t)h * DKK * DD, DD, DD,
              As, Bs, acc, t);
  float biasv[2];
#pragma unroll
  for (int nt = 0; nt < 2; ++nt) biasv[nt] = bias[h * DKK + 32 * nq + 16 * nt + l15];

  if (blockIdx.z < 2) {
    __syncthreads();
#pragma unroll
    for (int mt = 0; mt < 2; ++mt)
#pragma unroll
      for (int nt = 0; nt < 2; ++nt)
#pragma unroll
        for (int r = 0; r < 4; ++r)
          As[32 * mq + 16 * mt + l4 * 4 + r][32 * nq + 16 * nt + l15] =
              f2bf((acc[mt][nt][r] + biasv[nt]) * scale);
    __syncthreads();
#pragma unroll
    for (int i = 0; i < 2; ++i) {
      int c = t + i * 256;
      int row = c >> 3, cc = c & 7;
      int m = m0 + row, b = m >> 11, s = m & (SS - 1);
      uint4 v = *(const uint4*)&As[row][cc * 8];
      *(uint4*)(out + ((size_t)(b * HH + h) * SS + s) * DKK + cc * 8) = v;
    }
  } else {
#pragma unroll
    for (int mt = 0; mt < 2; ++mt)
#pragma unroll
      for (int nt = 0; nt < 2; ++nt) {
        int dk = 32 * nq + 16 * nt + l15;
        int m = m0 + 32 * mq + 16 * mt + l4 * 4;
        int b = m >> 11, sb = m & (SS - 1);
        ushort4 pk;
        pk.x = f2bf(acc[mt][nt][0] + biasv[nt]);
        pk.y = f2bf(acc[mt][nt][1] + biasv[nt]);
        pk.z = f2bf(acc[mt][nt][2] + biasv[nt]);
        pk.w = f2bf(acc[mt][nt][3] + biasv[nt]);
        *(ushort4*)(out + ((size_t)(b * HH + h) * DKK + dk) * SS + sb) = pk;
      }
  }
}

// ---------------- fused attention: single pass ----------------
// QK^T with SWAPPED operands: mfma(kf, qf) -> D[row=kj@(l4*4+r)][col=qi@l15]
// so each lane holds 4 consecutive kj for one qi -> vector P stores.
// P stored UNNORMALIZED (bf16 to pbuf, or fp32 to attn); rowsum accumulated in
// registers; PV uses unnormalized P; oacc scaled by 1/rowsum at the end.
// A separate memory-bound kernel normalizes the attn output.

template <int BF16P>
__global__ __launch_bounds__(256) void attn_kernel(
    const ushort* __restrict__ qb, const ushort* __restrict__ kb,
    const ushort* __restrict__ vt, void* __restrict__ pout,
    float* __restrict__ invb, ushort* __restrict__ ctx) {
  __shared__ ushort Ks[64][72], Vs[64][72], Ps[64][72];
  __shared__ float rs[64];
  const int t = threadIdx.x;
  const int l = t & 63, w = t >> 6;
  const int mq = w & 1, nq = w >> 1;
  const int l15 = l & 15, l4 = l >> 4;
  const int z = blockIdx.x;          // z-major grid: 2 z-slices per XCD
  const int q0 = blockIdx.y * 64;
  if (t < 64) rs[t] = 0.f;

  // Q fragments (already prescaled by 1/8) in registers
  short8 qf[2][2];
#pragma unroll
  for (int bt = 0; bt < 2; ++bt)
#pragma unroll
    for (int ks = 0; ks < 2; ++ks)
      qf[bt][ks] = *(const short8*)(qb +
          ((size_t)z * SS + q0 + 32 * mq + 16 * bt + l15) * DKK + ks * 32 + l4 * 8);

  int qi_[2]; float rowf[2];
#pragma unroll
  for (int bt = 0; bt < 2; ++bt) {
    qi_[bt] = q0 + 32 * mq + 16 * bt + l15;
    rowf[bt] = __expf(-0.02f * (float)qi_[bt]);
  }
  const float c_r[4] = {1.0f, 1.0202013f, 1.0408108f, 1.0618365f};  // exp(0.02 r)

  float rsp[2] = {0.f, 0.f};
  f32x4 oacc[2][2] = {};

  for (int kt = 0; kt < 32; ++kt) {
    __syncthreads();
#pragma unroll
    for (int i = 0; i < 2; ++i) {
      int c = t + i * 256;
      int row = c >> 3, cc = c & 7;
      *(uint4*)&Ks[row][cc * 8] =
          *(const uint4*)(kb + ((size_t)z * SS + kt * 64 + row) * DKK + cc * 8);
      *(uint4*)&Vs[row][cc * 8] =
          *(const uint4*)(vt + ((size_t)z * DKK + row) * SS + kt * 64 + cc * 8);
    }
    __syncthreads();
    // K as A-operand, Q as B-operand
    short8 kf[2][2];
#pragma unroll
    for (int at = 0; at < 2; ++at)
#pragma unroll
      for (int ks = 0; ks < 2; ++ks)
        kf[at][ks] = *(const short8*)&Ks[32 * nq + 16 * at + l15][ks * 32 + l4 * 8];
    f32x4 acc[2][2] = {};
#pragma unroll
    for (int at = 0; at < 2; ++at)
#pragma unroll
      for (int bt = 0; bt < 2; ++bt)
#pragma unroll
        for (int ks = 0; ks < 2; ++ks)
          acc[at][bt] = __builtin_amdgcn_mfma_f32_16x16x32_bf16(
              kf[at][ks], qf[bt][ks], acc[at][bt], 0, 0, 0);
    // epilogue: p = exp(score + bias), vector stores
#pragma unroll
    for (int at = 0; at < 2; ++at) {
      const int kjbase = kt * 64 + 32 * nq + 16 * at + l4 * 4;
      const float colb = __expf(0.02f * (float)kjbase);
#pragma unroll
      for (int bt = 0; bt < 2; ++bt) {
        const float rc = rowf[bt] * colb;
        ushort4 us;
        float pv[4];
#pragma unroll
        for (int r = 0; r < 4; ++r) {
          float bias = (kjbase + r <= qi_[bt]) ? rc * c_r[r] : 0.f;
          float p = __expf(acc[at][bt][r] + bias);
          pv[r] = p;
          rsp[bt] += p;
        }
        us.x = f2bf(pv[0]); us.y = f2bf(pv[1]);
        us.z = f2bf(pv[2]); us.w = f2bf(pv[3]);
        *(ushort4*)&Ps[32 * mq + 16 * bt + l15][32 * nq + 16 * at + l4 * 4] = us;
        const size_t gidx = ((size_t)z * SS + qi_[bt]) * SS + kjbase;
        if (BF16P) {
          *(ushort4*)((ushort*)pout + gidx) = us;
        } else {
          float4 f4 = {pv[0], pv[1], pv[2], pv[3]};
          *(float4*)((float*)pout + gidx) = f4;
        }
      }
    }
    __syncthreads();   // Ps ready
    short8 pa[2][2], pb[2][2];
#pragma unroll
    for (int mt = 0; mt < 2; ++mt)
#pragma unroll
      for (int ks = 0; ks < 2; ++ks)
        pa[mt][ks] = *(const short8*)&Ps[32 * mq + 16 * mt + l15][ks * 32 + l4 * 8];
#pragma unroll
    for (int nt = 0; nt < 2; ++nt)
#pragma unroll
      for (int ks = 0; ks < 2; ++ks)
        pb[nt][ks] = *(const short8*)&Vs[32 * nq + 16 * nt + l15][ks * 32 + l4 * 8];
#pragma unroll
    for (int mt = 0; mt < 2; ++mt)
#pragma unroll
      for (int nt = 0; nt < 2; ++nt)
#pragma unroll
        for (int ks = 0; ks < 2; ++ks)
          oacc[mt][nt] = __builtin_amdgcn_mfma_f32_16x16x32_bf16(
              pa[mt][ks], pb[nt][ks], oacc[mt][nt], 0, 0, 0);
  }

  // rowsum reduce: lanes sharing qi are l4 in {0..3} (xor 16,32) x 2 waves (nq)
#pragma unroll
  for (int bt = 0; bt < 2; ++bt) {
    float v = rsp[bt];
    v += __shfl_xor(v, 16);
    v += __shfl_xor(v, 32);
    if (l < 16) atomicAdd(&rs[32 * mq + 16 * bt + l], v);
  }
  __syncthreads();
  if (t < 64) invb[(size_t)z * SS + q0 + t] = 1.f / rs[t];
  // scale oacc by 1/rowsum (rows = qi at l4*4+r)
  float invr[2][4];
#pragma unroll
  for (int mt = 0; mt < 2; ++mt)
#pragma unroll
    for (int r = 0; r < 4; ++r)
      invr[mt][r] = 1.f / rs[32 * mq + 16 * mt + l4 * 4 + r];

  // epilogue: ctx tile via LDS bounce (Ps reuse; synced above)
#pragma unroll
  for (int mt = 0; mt < 2; ++mt)
#pragma unroll
    for (int nt = 0; nt < 2; ++nt)
#pragma unroll
      for (int r = 0; r < 4; ++r)
        Ps[32 * mq + 16 * mt + l4 * 4 + r][32 * nq + 16 * nt + l15] =
            f2bf(oacc[mt][nt][r] * invr[mt][r]);
  __syncthreads();
  const int b = z >> 3, h = z & 7;
#pragma unroll
  for (int i = 0; i < 2; ++i) {
    int c = t + i * 256;
    int row = c >> 3, cc = c & 7;
    uint4 v = *(const uint4*)&Ps[row][cc * 8];
    *(uint4*)(ctx + ((size_t)(b * SS + q0 + row)) * DD + h * DKK + cc * 8) = v;
  }
}

// ---------------- attn normalize (memory-bound) ----------------

__global__ __launch_bounds__(256) void scale_attn_bf(
    const ushort* __restrict__ pbuf, const float* __restrict__ invb,
    float* __restrict__ attn) {
  const size_t row = blockIdx.x;
  const float inv = invb[row];
  const int t = threadIdx.x;
  const size_t base = row * SS + t * 8;
  uint4 u = *(const uint4*)(pbuf + base);
  const ushort* us = (const ushort*)&u;
  float4 a, b;
  a.x = bf2f(us[0]) * inv; a.y = bf2f(us[1]) * inv;
  a.z = bf2f(us[2]) * inv; a.w = bf2f(us[3]) * inv;
  b.x = bf2f(us[4]) * inv; b.y = bf2f(us[5]) * inv;
  b.z = bf2f(us[6]) * inv; b.w = bf2f(us[7]) * inv;
  *(float4*)(attn + base) = a;
  *(float4*)(attn + base + 4) = b;
}

__global__ __launch_bounds__(256) void scale_attn_f32(
    float* __restrict__ attn, const float* __restrict__ invb) {
  const size_t row = blockIdx.x;
  const float inv = invb[row];
  const int t = threadIdx.x;
  const size_t base = row * SS + t * 8;
  float4 a = *(const float4*)(attn + base);
  float4 b = *(const float4*)(attn + base + 4);
  a.x *= inv; a.y *= inv; a.z *= inv; a.w *= inv;
  b.x *= inv; b.y *= inv; b.z *= inv; b.w *= inv;
  *(float4*)(attn + base) = a;
  *(float4*)(attn + base + 4) = b;
}

// ---------------- O projection ----------------

__global__ __launch_bounds__(256) void proj_o_kernel(
    const ushort* __restrict__ ctx, const ushort* __restrict__ wot,
    const float* __restrict__ bo, float* __restrict__ o) {
  __shared__ ushort As[64][72], Bs[64][72];
  const int m0 = blockIdx.x * 64, n0 = blockIdx.y * 64;
  const int t = threadIdx.x;
  const int l = t & 63, w = t >> 6;
  const int mq = w & 1, nq = w >> 1;
  const int l15 = l & 15, l4 = l >> 4;
  f32x4 acc[2][2] = {};
  mfma_gemm64(ctx + (size_t)m0 * DD, DD, wot + (size_t)n0 * DD, DD, DD,
              As, Bs, acc, t);
#pragma unroll
  for (int nt = 0; nt < 2; ++nt) {
    int col = n0 + 32 * nq + 16 * nt + l15;
    float bv = bo[col];
#pragma unroll
    for (int mt = 0; mt < 2; ++mt)
#pragma unroll
      for (int r = 0; r < 4; ++r) {
        int m = m0 + 32 * mq + 16 * mt + l4 * 4 + r;
        o[(size_t)m * DD + col] = acc[mt][nt][r] + bv;
      }
  }
}

// ---------------- gate MLP (fp32, small) ----------------

__global__ __launch_bounds__(256) void gate_kernel(
    const float* __restrict__ x, const float* __restrict__ g1w,
    const float* __restrict__ g1b, const float* __restrict__ g2w,
    const float* __restrict__ g2b, float* __restrict__ gate) {
  __shared__ float xs[8][512];
  __shared__ float red[32];
  const int r0 = blockIdx.x * 8;
  const int t = threadIdx.x;
  const float4* xg = (const float4*)&x[(size_t)r0 * DD];
  float4* xsv = (float4*)&xs[0][0];
#pragma unroll
  for (int i = 0; i < 4; ++i) xsv[t + i * 256] = xg[t + i * 256];
  __syncthreads();
  float acc[8] = {};
  for (int i = 0; i < 512; i += 4) {
    float w0 = g1w[(i + 0) * 256 + t];
    float w1 = g1w[(i + 1) * 256 + t];
    float w2 = g1w[(i + 2) * 256 + t];
    float w3 = g1w[(i + 3) * 256 + t];
#pragma unroll
    for (int r = 0; r < 8; ++r) {
      float4 xv = *(const float4*)&xs[r][i];
      acc[r] += xv.x * w0 + xv.y * w1 + xv.z * w2 + xv.w * w3;
    }
  }
  float b1 = g1b[t], w2_ = g2w[t];
  float p[8];
#pragma unroll
  for (int r = 0; r < 8; ++r) {
    float h = acc[r] + b1;
    h = h > 0.f ? h : 0.f;
    p[r] = h * w2_;
  }
#pragma unroll
  for (int r = 0; r < 8; ++r)
    for (int off = 32; off; off >>= 1) p[r] += __shfl_xor(p[r], off, 64);
  if ((t & 63) == 0) {
#pragma unroll
    for (int r = 0; r < 8; ++r) red[r * 4 + (t >> 6)] = p[r];
  }
  __syncthreads();
  if (t < 8) {
    float s = red[t * 4] + red[t * 4 + 1] + red[t * 4 + 2] + red[t * 4 + 3] + g2b[0];
    gate[r0 + t] = 1.f / (1.f + __expf(-s));
  }
}

// ---------------- gated blend + layernorm ----------------

__global__ __launch_bounds__(256) void blend_ln_kernel(
    const float* __restrict__ o, const float* __restrict__ x,
    const float* __restrict__ gate, const float* __restrict__ ln_g,
    const float* __restrict__ ln_b, float* __restrict__ y) {
  __shared__ float r1[4], r2[4];
  const int row = blockIdx.x, t = threadIdx.x;
  float g = gate[row];
  float2 o2 = *(const float2*)&o[(size_t)row * DD + t * 2];
  float2 x2 = *(const float2*)&x[(size_t)row * DD + t * 2];
  float va = o2.x * g + x2.x * (1.f - g);
  float vb = o2.y * g + x2.y * (1.f - g);
  float s = va + vb, q = va * va + vb * vb;
  for (int off = 32; off; off >>= 1) {
    s += __shfl_xor(s, off, 64);
    q += __shfl_xor(q, off, 64);
  }
  if ((t & 63) == 0) { r1[t >> 6] = s; r2[t >> 6] = q; }
  __syncthreads();
  s = r1[0] + r1[1] + r1[2] + r1[3];
  q = r2[0] + r2[1] + r2[2] + r2[3];
  float mean = s * (1.f / 512.f);
  float var = q * (1.f / 512.f) - mean * mean;
  float rstd = rsqrtf(var + 1e-5f);
  float2 lg = *(const float2*)&ln_g[t * 2];
  float2 lb = *(const float2*)&ln_b[t * 2];
  float2 out;
  out.x = (va - mean) * rstd * lg.x + lb.x;
  out.y = (vb - mean) * rstd * lg.y + lb.y;
  *(float2*)&y[(size_t)row * DD + t * 2] = out;
}

extern "C" void kernel_launch(void* const* d_in, const int* in_sizes, int n_in,
                              void* d_out, int out_size, void* d_ws, size_t ws_size,
                              hipStream_t stream) {
  const float* x   = (const float*)d_in[0];
  const float* wq  = (const float*)d_in[1];
  const float* bq  = (const float*)d_in[2];
  const float* wk  = (const float*)d_in[3];
  const float* bk  = (const float*)d_in[4];
  const float* wv  = (const float*)d_in[5];
  const float* bv  = (const float*)d_in[6];
  const float* wo  = (const float*)d_in[7];
  const float* bo  = (const float*)d_in[8];
  const float* g1w = (const float*)d_in[9];
  const float* g1b = (const float*)d_in[10];
  const float* g2w = (const float*)d_in[11];
  const float* g2b = (const float*)d_in[12];
  const float* lng = (const float*)d_in[13];
  const float* lnb = (const float*)d_in[14];

  float* y    = (float*)d_out;
  float* attn = y + (size_t)Y_SIZE;

  char* ws = (char*)d_ws;
  ushort* xb  = (ushort*)(ws);                       // 4 MB
  ushort* wqt = (ushort*)(ws + (4 << 20));           // 512 KB
  ushort* wkt = (ushort*)(ws + (4 << 20) + (512 << 10));
  ushort* wvt = (ushort*)(ws + (5 << 20));
  ushort* wot = (ushort*)(ws + (5 << 20) + (512 << 10));
  ushort* qb  = (ushort*)(ws + (6 << 20));           // 4 MB
  ushort* kb  = (ushort*)(ws + (10 << 20));          // 4 MB
  ushort* vt  = (ushort*)(ws + (14 << 20));          // 4 MB
  ushort* ctx = (ushort*)(ws + (18 << 20));          // 4 MB
  float*  o   = (float*)(ws + (22 << 20));           // 8 MB
  float*  gate= (float*)(ws + (30 << 20));           // 16 KB
  float*  invb= (float*)(ws + (30 << 20) + (256 << 10)); // 128 KB
  ushort* pbuf= (ushort*)(ws + (32 << 20));          // 128 MB (optional)

  const bool bigws = ws_size >= ((size_t)168 << 20);

  hipLaunchKernelGGL(conv_x_kernel, dim3(Y_SIZE / 1024), dim3(256), 0, stream, x, xb);
  hipLaunchKernelGGL(conv_wt_kernel, dim3(8, 8, 4), dim3(256), 0, stream,
                     wq, wk, wv, wo, wqt, wkt, wvt, wot);
  hipLaunchKernelGGL(proj_qkv_kernel, dim3(64, 8, 3), dim3(256), 0, stream,
                     xb, wqt, bq, wkt, bk, wvt, bv, qb, kb, vt);
  hipLaunchKernelGGL(gate_kernel, dim3(512), dim3(256), 0, stream,
                     x, g1w, g1b, g2w, g2b, gate);
  if (bigws) {
    hipLaunchKernelGGL(attn_kernel<1>, dim3(16, 32), dim3(256), 0, stream,
                       qb, kb, vt, (void*)pbuf, invb, ctx);
    hipLaunchKernelGGL(scale_attn_bf, dim3(BB * HH * SS), dim3(256), 0, stream,
                       pbuf, invb, attn);
  } else {
    hipLaunchKernelGGL(attn_kernel<0>, dim3(16, 32), dim3(256), 0, stream,
                       qb, kb, vt, (void*)attn, invb, ctx);
    hipLaunchKernelGGL(scale_attn_f32, dim3(BB * HH * SS), dim3(256), 0, stream,
                       attn, invb);
  }
  hipLaunchKernelGGL(proj_o_kernel, dim3(64, 8), dim3(256), 0, stream,
                     ctx, wot, bo, o);
  hipLaunchKernelGGL(blend_ln_kernel, dim3(4096), dim3(256), 0, stream,
                     o, x, gate, lng, lnb, y);
}

// Round 3
// 458.858 us; speedup vs baseline: 1.0807x; 1.0562x over previous
//
#include <hip/hip_runtime.h>

#define BB 2
#define SS 2048
#define DD 512
#define HH 8
#define DKK 64
#define NROWS (BB * SS)          // 4096
#define Y_SIZE (BB * SS * DD)    // 2097152

typedef __attribute__((ext_vector_type(8))) short short8;
typedef __attribute__((ext_vector_type(4))) float f32x4;

__device__ __forceinline__ ushort f2bf(float f) {
  union { float f; unsigned u; } v; v.f = f;
  unsigned u = v.u;
  return (ushort)((u + 0x7fffu + ((u >> 16) & 1u)) >> 16);
}

// ---------------- converts ----------------

__global__ __launch_bounds__(256) void conv_x_kernel(const float* __restrict__ x,
                                                     ushort* __restrict__ xb) {
  int i = (blockIdx.x * 256 + threadIdx.x) * 4;
  float4 v = *(const float4*)(x + i);
  ushort4 o = {f2bf(v.x), f2bf(v.y), f2bf(v.z), f2bf(v.w)};
  *(ushort4*)(xb + i) = o;
}

// transpose 512x512 fp32 w[k][n] -> bf16 wt[n][k]
__global__ __launch_bounds__(256) void conv_wt_kernel(
    const float* __restrict__ w0, const float* __restrict__ w1,
    const float* __restrict__ w2, const float* __restrict__ w3,
    ushort* __restrict__ o0, ushort* __restrict__ o1,
    ushort* __restrict__ o2, ushort* __restrict__ o3) {
  __shared__ float T[64][65];
  const float* w; ushort* wt;
  switch (blockIdx.z) {
    case 0: w = w0; wt = o0; break;
    case 1: w = w1; wt = o1; break;
    case 2: w = w2; wt = o2; break;
    default: w = w3; wt = o3; break;
  }
  const int t = threadIdx.x;
  const int n0 = blockIdx.x * 64, k0 = blockIdx.y * 64;
#pragma unroll
  for (int i = 0; i < 4; ++i) {
    int c = t + i * 256;
    int row = c >> 4, cc = c & 15;
    float4 v = *(const float4*)(w + (size_t)(k0 + row) * DD + n0 + cc * 4);
    T[row][cc * 4 + 0] = v.x; T[row][cc * 4 + 1] = v.y;
    T[row][cc * 4 + 2] = v.z; T[row][cc * 4 + 3] = v.w;
  }
  __syncthreads();
#pragma unroll
  for (int i = 0; i < 2; ++i) {
    int c = t + i * 256;
    int nr = c >> 3, kc = c & 7;
    ushort4 a, b;
    a.x = f2bf(T[kc * 8 + 0][nr]); a.y = f2bf(T[kc * 8 + 1][nr]);
    a.z = f2bf(T[kc * 8 + 2][nr]); a.w = f2bf(T[kc * 8 + 3][nr]);
    b.x = f2bf(T[kc * 8 + 4][nr]); b.y = f2bf(T[kc * 8 + 5][nr]);
    b.z = f2bf(T[kc * 8 + 6][nr]); b.w = f2bf(T[kc * 8 + 7][nr]);
    *(ushort4*)(wt + (size_t)(n0 + nr) * DD + k0 + kc * 8) = a;
    *(ushort4*)(wt + (size_t)(n0 + nr) * DD + k0 + kc * 8 + 4) = b;
  }
}

// ---------------- shared MFMA GEMM body: 64x64 tile, BK=64, NT form ----------

__device__ __forceinline__ void mfma_gemm64(
    const ushort* __restrict__ A, int lda, const ushort* __restrict__ B, int ldb,
    int K, ushort (*As)[72], ushort (*Bs)[72], f32x4 (&acc)[2][2], int t) {
  const int l = t & 63, w = t >> 6;
  const int mq = w & 1, nq = w >> 1;
  const int l15 = l & 15, l4 = l >> 4;
  for (int k0 = 0; k0 < K; k0 += 64) {
    __syncthreads();
#pragma unroll
    for (int i = 0; i < 2; ++i) {
      int c = t + i * 256;
      int row = c >> 3, cc = c & 7;
      *(uint4*)&As[row][cc * 8] = *(const uint4*)(A + (size_t)row * lda + k0 + cc * 8);
      *(uint4*)&Bs[row][cc * 8] = *(const uint4*)(B + (size_t)row * ldb + k0 + cc * 8);
    }
    __syncthreads();
    short8 af[2][2], bf[2][2];
#pragma unroll
    for (int mt = 0; mt < 2; ++mt)
#pragma unroll
      for (int ks = 0; ks < 2; ++ks)
        af[mt][ks] = *(const short8*)&As[32 * mq + 16 * mt + l15][ks * 32 + l4 * 8];
#pragma unroll
    for (int nt = 0; nt < 2; ++nt)
#pragma unroll
      for (int ks = 0; ks < 2; ++ks)
        bf[nt][ks] = *(const short8*)&Bs[32 * nq + 16 * nt + l15][ks * 32 + l4 * 8];
#pragma unroll
    for (int mt = 0; mt < 2; ++mt)
#pragma unroll
      for (int nt = 0; nt < 2; ++nt)
#pragma unroll
        for (int ks = 0; ks < 2; ++ks)
          acc[mt][nt] = __builtin_amdgcn_mfma_f32_16x16x32_bf16(
              af[mt][ks], bf[nt][ks], acc[mt][nt], 0, 0, 0);
  }
}

// ---------------- QKV projection ----------------
// out: q (prescaled by 1/8), k as bf16 [z][s][dk]; v transposed bf16 [z][dk][s]

__global__ __launch_bounds__(256) void proj_qkv_kernel(
    const ushort* __restrict__ xb,
    const ushort* __restrict__ wqt, const float* __restrict__ bq,
    const ushort* __restrict__ wkt, const float* __restrict__ bk,
    const ushort* __restrict__ wvt, const float* __restrict__ bv,
    ushort* __restrict__ qb, ushort* __restrict__ kb, ushort* __restrict__ vt) {
  __shared__ ushort As[64][72], Bs[64][72];
  const ushort* W; const float* bias; ushort* out;
  if (blockIdx.z == 0) { W = wqt; bias = bq; out = qb; }
  else if (blockIdx.z == 1) { W = wkt; bias = bk; out = kb; }
  else { W = wvt; bias = bv; out = vt; }
  const float scale = (blockIdx.z == 0) ? 0.125f : 1.0f;  // fold 1/sqrt(dk) into Q
  const int m0 = blockIdx.x * 64;
  const int h = blockIdx.y;
  const int t = threadIdx.x;
  const int l = t & 63, w = t >> 6;
  const int mq = w & 1, nq = w >> 1;
  const int l15 = l & 15, l4 = l >> 4;
  f32x4 acc[2][2] = {};
  mfma_gemm64(xb + (size_t)m0 * DD, DD, W + (size_t)h * DKK * DD, DD, DD,
              As, Bs, acc, t);
  float biasv[2];
#pragma unroll
  for (int nt = 0; nt < 2; ++nt) biasv[nt] = bias[h * DKK + 32 * nq + 16 * nt + l15];

  if (blockIdx.z < 2) {
    __syncthreads();
#pragma unroll
    for (int mt = 0; mt < 2; ++mt)
#pragma unroll
      for (int nt = 0; nt < 2; ++nt)
#pragma unroll
        for (int r = 0; r < 4; ++r)
          As[32 * mq + 16 * mt + l4 * 4 + r][32 * nq + 16 * nt + l15] =
              f2bf((acc[mt][nt][r] + biasv[nt]) * scale);
    __syncthreads();
#pragma unroll
    for (int i = 0; i < 2; ++i) {
      int c = t + i * 256;
      int row = c >> 3, cc = c & 7;
      int m = m0 + row, b = m >> 11, s = m & (SS - 1);
      uint4 v = *(const uint4*)&As[row][cc * 8];
      *(uint4*)(out + ((size_t)(b * HH + h) * SS + s) * DKK + cc * 8) = v;
    }
  } else {
#pragma unroll
    for (int mt = 0; mt < 2; ++mt)
#pragma unroll
      for (int nt = 0; nt < 2; ++nt) {
        int dk = 32 * nq + 16 * nt + l15;
        int m = m0 + 32 * mq + 16 * mt + l4 * 4;
        int b = m >> 11, sb = m & (SS - 1);
        ushort4 pk;
        pk.x = f2bf(acc[mt][nt][0] + biasv[nt]);
        pk.y = f2bf(acc[mt][nt][1] + biasv[nt]);
        pk.z = f2bf(acc[mt][nt][2] + biasv[nt]);
        pk.w = f2bf(acc[mt][nt][3] + biasv[nt]);
        *(ushort4*)(out + ((size_t)(b * HH + h) * DKK + dk) * SS + sb) = pk;
      }
  }
}

// ---------------- fused attention: two phases, one kernel ----------------
// QK^T with SWAPPED operands: mfma(kf, qf) -> lane holds 4 consecutive kj for
// one qi -> vector stores.
// Phase 1: K,V staged; p=exp(score+bias) unnormalized; rowsum in regs; P->LDS
//          bf16; PV accumulate. NO global P traffic.
// Then: rowsum reduce; ctx tile written (oacc * 1/rowsum).
// Phase 2: K-only, double-buffered (Ks/Vs alternate), QK^T recomputed,
//          normalized fp32 attn written directly (exact 268 MB, float4).
// Grid dim3(32,16): qtile fastest -> consecutive blocks share z (K/V L2 reuse).

__global__ __launch_bounds__(256) void attn_kernel(
    const ushort* __restrict__ qb, const ushort* __restrict__ kb,
    const ushort* __restrict__ vt, float* __restrict__ attn,
    ushort* __restrict__ ctx) {
  __shared__ ushort Ks[64][72], Vs[64][72], Ps[64][72];
  __shared__ float rs[64];
  const int t = threadIdx.x;
  const int l = t & 63, w = t >> 6;
  const int mq = w & 1, nq = w >> 1;
  const int l15 = l & 15, l4 = l >> 4;
  const int z = blockIdx.y;
  const int q0 = blockIdx.x * 64;
  if (t < 64) rs[t] = 0.f;

  // Q fragments (already prescaled by 1/8) in registers
  short8 qf[2][2];
#pragma unroll
  for (int bt = 0; bt < 2; ++bt)
#pragma unroll
    for (int ks = 0; ks < 2; ++ks)
      qf[bt][ks] = *(const short8*)(qb +
          ((size_t)z * SS + q0 + 32 * mq + 16 * bt + l15) * DKK + ks * 32 + l4 * 8);

  int qi_[2]; float rowf[2];
#pragma unroll
  for (int bt = 0; bt < 2; ++bt) {
    qi_[bt] = q0 + 32 * mq + 16 * bt + l15;
    rowf[bt] = __expf(-0.02f * (float)qi_[bt]);
  }
  const float c_r[4] = {1.0f, 1.0202013f, 1.0408108f, 1.0618365f};  // exp(0.02 r)

  float rsp[2] = {0.f, 0.f};
  f32x4 oacc[2][2] = {};

  // ---- phase 1: rowsums + PV (no global P stores) ----
  for (int kt = 0; kt < 32; ++kt) {
    __syncthreads();
#pragma unroll
    for (int i = 0; i < 2; ++i) {
      int c = t + i * 256;
      int row = c >> 3, cc = c & 7;
      *(uint4*)&Ks[row][cc * 8] =
          *(const uint4*)(kb + ((size_t)z * SS + kt * 64 + row) * DKK + cc * 8);
      *(uint4*)&Vs[row][cc * 8] =
          *(const uint4*)(vt + ((size_t)z * DKK + row) * SS + kt * 64 + cc * 8);
    }
    __syncthreads();
    short8 kf[2][2];
#pragma unroll
    for (int at = 0; at < 2; ++at)
#pragma unroll
      for (int ks = 0; ks < 2; ++ks)
        kf[at][ks] = *(const short8*)&Ks[32 * nq + 16 * at + l15][ks * 32 + l4 * 8];
    f32x4 acc[2][2] = {};
#pragma unroll
    for (int at = 0; at < 2; ++at)
#pragma unroll
      for (int bt = 0; bt < 2; ++bt)
#pragma unroll
        for (int ks = 0; ks < 2; ++ks)
          acc[at][bt] = __builtin_amdgcn_mfma_f32_16x16x32_bf16(
              kf[at][ks], qf[bt][ks], acc[at][bt], 0, 0, 0);
#pragma unroll
    for (int at = 0; at < 2; ++at) {
      const int kjbase = kt * 64 + 32 * nq + 16 * at + l4 * 4;
      const float colb = __expf(0.02f * (float)kjbase);
#pragma unroll
      for (int bt = 0; bt < 2; ++bt) {
        const float rc = rowf[bt] * colb;
        ushort4 us;
        float pv[4];
#pragma unroll
        for (int r = 0; r < 4; ++r) {
          float bias = (kjbase + r <= qi_[bt]) ? rc * c_r[r] : 0.f;
          float p = __expf(acc[at][bt][r] + bias);
          pv[r] = p;
          rsp[bt] += p;
        }
        us.x = f2bf(pv[0]); us.y = f2bf(pv[1]);
        us.z = f2bf(pv[2]); us.w = f2bf(pv[3]);
        *(ushort4*)&Ps[32 * mq + 16 * bt + l15][32 * nq + 16 * at + l4 * 4] = us;
      }
    }
    __syncthreads();   // Ps ready
    short8 pa[2][2], pb[2][2];
#pragma unroll
    for (int mt = 0; mt < 2; ++mt)
#pragma unroll
      for (int ks = 0; ks < 2; ++ks)
        pa[mt][ks] = *(const short8*)&Ps[32 * mq + 16 * mt + l15][ks * 32 + l4 * 8];
#pragma unroll
    for (int nt = 0; nt < 2; ++nt)
#pragma unroll
      for (int ks = 0; ks < 2; ++ks)
        pb[nt][ks] = *(const short8*)&Vs[32 * nq + 16 * nt + l15][ks * 32 + l4 * 8];
#pragma unroll
    for (int mt = 0; mt < 2; ++mt)
#pragma unroll
      for (int nt = 0; nt < 2; ++nt)
#pragma unroll
        for (int ks = 0; ks < 2; ++ks)
          oacc[mt][nt] = __builtin_amdgcn_mfma_f32_16x16x32_bf16(
              pa[mt][ks], pb[nt][ks], oacc[mt][nt], 0, 0, 0);
  }

  // rowsum reduce: lanes sharing qi differ in l4 (xor 16,32) x 2 waves (nq)
#pragma unroll
  for (int bt = 0; bt < 2; ++bt) {
    float v = rsp[bt];
    v += __shfl_xor(v, 16);
    v += __shfl_xor(v, 32);
    if (l < 16) atomicAdd(&rs[32 * mq + 16 * bt + l], v);
  }
  __syncthreads();
  // phase-2 normalizers (row = qi_[bt] at col index l15)
  float invq[2];
#pragma unroll
  for (int bt = 0; bt < 2; ++bt) invq[bt] = 1.f / rs[32 * mq + 16 * bt + l15];
  // ctx normalizers (rows = l4*4+r)
  float invr[2][4];
#pragma unroll
  for (int mt = 0; mt < 2; ++mt)
#pragma unroll
    for (int r = 0; r < 4; ++r)
      invr[mt][r] = 1.f / rs[32 * mq + 16 * mt + l4 * 4 + r];

  // ctx epilogue via LDS bounce (Ps reuse; all PV reads done: synced above)
#pragma unroll
  for (int mt = 0; mt < 2; ++mt)
#pragma unroll
    for (int nt = 0; nt < 2; ++nt)
#pragma unroll
      for (int r = 0; r < 4; ++r)
        Ps[32 * mq + 16 * mt + l4 * 4 + r][32 * nq + 16 * nt + l15] =
            f2bf(oacc[mt][nt][r] * invr[mt][r]);
  __syncthreads();
  {
    const int b = z >> 3, h = z & 7;
#pragma unroll
    for (int i = 0; i < 2; ++i) {
      int c = t + i * 256;
      int row = c >> 3, cc = c & 7;
      uint4 v = *(const uint4*)&Ps[row][cc * 8];
      *(uint4*)(ctx + ((size_t)(b * SS + q0 + row)) * DD + h * DKK + cc * 8) = v;
    }
  }

  // ---- phase 2: recompute QK^T, write normalized fp32 attn ----
  // K double-buffered in Ks (even kt) / Vs (odd kt): 1 barrier per iter.
  const int srow = t >> 3, scol = (t & 7) * 8;   // staging: 2 rows/thread
  const int srow2 = srow + 32;
  __syncthreads();   // ctx LDS reads complete before any buffer reuse
  {
    const ushort* p = kb + (size_t)z * SS * DKK;
    *(uint4*)&Ks[srow][scol]  = *(const uint4*)(p + (size_t)srow * DKK + scol);
    *(uint4*)&Ks[srow2][scol] = *(const uint4*)(p + (size_t)srow2 * DKK + scol);
  }
  __syncthreads();
  for (int kt = 0; kt < 32; ++kt) {
    ushort (*cur)[72] = (kt & 1) ? Vs : Ks;
    ushort (*nxt)[72] = (kt & 1) ? Ks : Vs;
    uint4 s0, s1;
    if (kt < 31) {
      const ushort* p = kb + ((size_t)z * SS + (kt + 1) * 64) * DKK;
      s0 = *(const uint4*)(p + (size_t)srow * DKK + scol);
      s1 = *(const uint4*)(p + (size_t)srow2 * DKK + scol);
    }
    short8 kf[2][2];
#pragma unroll
    for (int at = 0; at < 2; ++at)
#pragma unroll
      for (int ks = 0; ks < 2; ++ks)
        kf[at][ks] = *(const short8*)&cur[32 * nq + 16 * at + l15][ks * 32 + l4 * 8];
    f32x4 acc[2][2] = {};
#pragma unroll
    for (int at = 0; at < 2; ++at)
#pragma unroll
      for (int bt = 0; bt < 2; ++bt)
#pragma unroll
        for (int ks = 0; ks < 2; ++ks)
          acc[at][bt] = __builtin_amdgcn_mfma_f32_16x16x32_bf16(
              kf[at][ks], qf[bt][ks], acc[at][bt], 0, 0, 0);
#pragma unroll
    for (int at = 0; at < 2; ++at) {
      const int kjbase = kt * 64 + 32 * nq + 16 * at + l4 * 4;
      const float colb = __expf(0.02f * (float)kjbase);
#pragma unroll
      for (int bt = 0; bt < 2; ++bt) {
        const float rc = rowf[bt] * colb;
        float4 f4;
#pragma unroll
        for (int r = 0; r < 4; ++r) {
          float bias = (kjbase + r <= qi_[bt]) ? rc * c_r[r] : 0.f;
          float p = __expf(acc[at][bt][r] + bias) * invq[bt];
          ((float*)&f4)[r] = p;
        }
        *(float4*)(attn + ((size_t)z * SS + qi_[bt]) * SS + kjbase) = f4;
      }
    }
    if (kt < 31) {
      *(uint4*)&nxt[srow][scol]  = s0;
      *(uint4*)&nxt[srow2][scol] = s1;
    }
    __syncthreads();
  }
}

// ---------------- O projection ----------------

__global__ __launch_bounds__(256) void proj_o_kernel(
    const ushort* __restrict__ ctx, const ushort* __restrict__ wot,
    const float* __restrict__ bo, float* __restrict__ o) {
  __shared__ ushort As[64][72], Bs[64][72];
  const int m0 = blockIdx.x * 64, n0 = blockIdx.y * 64;
  const int t = threadIdx.x;
  const int l = t & 63, w = t >> 6;
  const int mq = w & 1, nq = w >> 1;
  const int l15 = l & 15, l4 = l >> 4;
  f32x4 acc[2][2] = {};
  mfma_gemm64(ctx + (size_t)m0 * DD, DD, wot + (size_t)n0 * DD, DD, DD,
              As, Bs, acc, t);
#pragma unroll
  for (int nt = 0; nt < 2; ++nt) {
    int col = n0 + 32 * nq + 16 * nt + l15;
    float bv = bo[col];
#pragma unroll
    for (int mt = 0; mt < 2; ++mt)
#pragma unroll
      for (int r = 0; r < 4; ++r) {
        int m = m0 + 32 * mq + 16 * mt + l4 * 4 + r;
        o[(size_t)m * DD + col] = acc[mt][nt][r] + bv;
      }
  }
}

// ---------------- gate MLP (fp32, small) ----------------

__global__ __launch_bounds__(256) void gate_kernel(
    const float* __restrict__ x, const float* __restrict__ g1w,
    const float* __restrict__ g1b, const float* __restrict__ g2w,
    const float* __restrict__ g2b, float* __restrict__ gate) {
  __shared__ float xs[8][512];
  __shared__ float red[32];
  const int r0 = blockIdx.x * 8;
  const int t = threadIdx.x;
  const float4* xg = (const float4*)&x[(size_t)r0 * DD];
  float4* xsv = (float4*)&xs[0][0];
#pragma unroll
  for (int i = 0; i < 4; ++i) xsv[t + i * 256] = xg[t + i * 256];
  __syncthreads();
  float acc[8] = {};
  for (int i = 0; i < 512; i += 4) {
    float w0 = g1w[(i + 0) * 256 + t];
    float w1 = g1w[(i + 1) * 256 + t];
    float w2 = g1w[(i + 2) * 256 + t];
    float w3 = g1w[(i + 3) * 256 + t];
#pragma unroll
    for (int r = 0; r < 8; ++r) {
      float4 xv = *(const float4*)&xs[r][i];
      acc[r] += xv.x * w0 + xv.y * w1 + xv.z * w2 + xv.w * w3;
    }
  }
  float b1 = g1b[t], w2_ = g2w[t];
  float p[8];
#pragma unroll
  for (int r = 0; r < 8; ++r) {
    float h = acc[r] + b1;
    h = h > 0.f ? h : 0.f;
    p[r] = h * w2_;
  }
#pragma unroll
  for (int r = 0; r < 8; ++r)
    for (int off = 32; off; off >>= 1) p[r] += __shfl_xor(p[r], off, 64);
  if ((t & 63) == 0) {
#pragma unroll
    for (int r = 0; r < 8; ++r) red[r * 4 + (t >> 6)] = p[r];
  }
  __syncthreads();
  if (t < 8) {
    float s = red[t * 4] + red[t * 4 + 1] + red[t * 4 + 2] + red[t * 4 + 3] + g2b[0];
    gate[r0 + t] = 1.f / (1.f + __expf(-s));
  }
}

// ---------------- gated blend + layernorm ----------------

__global__ __launch_bounds__(256) void blend_ln_kernel(
    const float* __restrict__ o, const float* __restrict__ x,
    const float* __restrict__ gate, const float* __restrict__ ln_g,
    const float* __restrict__ ln_b, float* __restrict__ y) {
  __shared__ float r1[4], r2[4];
  const int row = blockIdx.x, t = threadIdx.x;
  float g = gate[row];
  float2 o2 = *(const float2*)&o[(size_t)row * DD + t * 2];
  float2 x2 = *(const float2*)&x[(size_t)row * DD + t * 2];
  float va = o2.x * g + x2.x * (1.f - g);
  float vb = o2.y * g + x2.y * (1.f - g);
  float s = va + vb, q = va * va + vb * vb;
  for (int off = 32; off; off >>= 1) {
    s += __shfl_xor(s, off, 64);
    q += __shfl_xor(q, off, 64);
  }
  if ((t & 63) == 0) { r1[t >> 6] = s; r2[t >> 6] = q; }
  __syncthreads();
  s = r1[0] + r1[1] + r1[2] + r1[3];
  q = r2[0] + r2[1] + r2[2] + r2[3];
  float mean = s * (1.f / 512.f);
  float var = q * (1.f / 512.f) - mean * mean;
  float rstd = rsqrtf(var + 1e-5f);
  float2 lg = *(const float2*)&ln_g[t * 2];
  float2 lb = *(const float2*)&ln_b[t * 2];
  float2 out;
  out.x = (va - mean) * rstd * lg.x + lb.x;
  out.y = (vb - mean) * rstd * lg.y + lb.y;
  *(float2*)&y[(size_t)row * DD + t * 2] = out;
}

extern "C" void kernel_launch(void* const* d_in, const int* in_sizes, int n_in,
                              void* d_out, int out_size, void* d_ws, size_t ws_size,
                              hipStream_t stream) {
  const float* x   = (const float*)d_in[0];
  const float* wq  = (const float*)d_in[1];
  const float* bq  = (const float*)d_in[2];
  const float* wk  = (const float*)d_in[3];
  const float* bk  = (const float*)d_in[4];
  const float* wv  = (const float*)d_in[5];
  const float* bv  = (const float*)d_in[6];
  const float* wo  = (const float*)d_in[7];
  const float* bo  = (const float*)d_in[8];
  const float* g1w = (const float*)d_in[9];
  const float* g1b = (const float*)d_in[10];
  const float* g2w = (const float*)d_in[11];
  const float* g2b = (const float*)d_in[12];
  const float* lng = (const float*)d_in[13];
  const float* lnb = (const float*)d_in[14];

  float* y    = (float*)d_out;
  float* attn = y + (size_t)Y_SIZE;

  char* ws = (char*)d_ws;
  ushort* xb  = (ushort*)(ws);                       // 4 MB
  ushort* wqt = (ushort*)(ws + (4 << 20));           // 512 KB
  ushort* wkt = (ushort*)(ws + (4 << 20) + (512 << 10));
  ushort* wvt = (ushort*)(ws + (5 << 20));
  ushort* wot = (ushort*)(ws + (5 << 20) + (512 << 10));
  ushort* qb  = (ushort*)(ws + (6 << 20));           // 4 MB
  ushort* kb  = (ushort*)(ws + (10 << 20));          // 4 MB
  ushort* vt  = (ushort*)(ws + (14 << 20));          // 4 MB
  ushort* ctx = (ushort*)(ws + (18 << 20));          // 4 MB
  float*  o   = (float*)(ws + (22 << 20));           // 8 MB
  float*  gate= (float*)(ws + (30 << 20));           // 16 KB

  hipLaunchKernelGGL(conv_x_kernel, dim3(Y_SIZE / 1024), dim3(256), 0, stream, x, xb);
  hipLaunchKernelGGL(conv_wt_kernel, dim3(8, 8, 4), dim3(256), 0, stream,
                     wq, wk, wv, wo, wqt, wkt, wvt, wot);
  hipLaunchKernelGGL(proj_qkv_kernel, dim3(64, 8, 3), dim3(256), 0, stream,
                     xb, wqt, bq, wkt, bk, wvt, bv, qb, kb, vt);
  hipLaunchKernelGGL(gate_kernel, dim3(512), dim3(256), 0, stream,
                     x, g1w, g1b, g2w, g2b, gate);
  hipLaunchKernelGGL(attn_kernel, dim3(32, 16), dim3(256), 0, stream,
                     qb, kb, vt, attn, ctx);
  hipLaunchKernelGGL(proj_o_kernel, dim3(64, 8), dim3(256), 0, stream,
                     ctx, wot, bo, o);
  hipLaunchKernelGGL(blend_ln_kernel, dim3(4096), dim3(256), 0, stream,
                     o, x, gate, lng, lnb, y);
}

// Round 4
// 458.250 us; speedup vs baseline: 1.0821x; 1.0013x over previous
//
#include <hip/hip_runtime.h>

#define BB 2
#define SS 2048
#define DD 512
#define HH 8
#define DKK 64
#define NROWS (BB * SS)          // 4096
#define Y_SIZE (BB * SS * DD)    // 2097152

typedef __attribute__((ext_vector_type(8))) short short8;
typedef __attribute__((ext_vector_type(4))) float f32x4;

__device__ __forceinline__ ushort f2bf(float f) {
  union { float f; unsigned u; } v; v.f = f;
  unsigned u = v.u;
  return (ushort)((u + 0x7fffu + ((u >> 16) & 1u)) >> 16);
}

// ---------------- converts ----------------

__global__ __launch_bounds__(256) void conv_x_kernel(const float* __restrict__ x,
                                                     ushort* __restrict__ xb) {
  int i = (blockIdx.x * 256 + threadIdx.x) * 4;
  float4 v = *(const float4*)(x + i);
  ushort4 o = {f2bf(v.x), f2bf(v.y), f2bf(v.z), f2bf(v.w)};
  *(ushort4*)(xb + i) = o;
}

// transpose 512x512 fp32 w[k][n] -> bf16 wt[n][k]
__global__ __launch_bounds__(256) void conv_wt_kernel(
    const float* __restrict__ w0, const float* __restrict__ w1,
    const float* __restrict__ w2, const float* __restrict__ w3,
    ushort* __restrict__ o0, ushort* __restrict__ o1,
    ushort* __restrict__ o2, ushort* __restrict__ o3) {
  __shared__ float T[64][65];
  const float* w; ushort* wt;
  switch (blockIdx.z) {
    case 0: w = w0; wt = o0; break;
    case 1: w = w1; wt = o1; break;
    case 2: w = w2; wt = o2; break;
    default: w = w3; wt = o3; break;
  }
  const int t = threadIdx.x;
  const int n0 = blockIdx.x * 64, k0 = blockIdx.y * 64;
#pragma unroll
  for (int i = 0; i < 4; ++i) {
    int c = t + i * 256;
    int row = c >> 4, cc = c & 15;
    float4 v = *(const float4*)(w + (size_t)(k0 + row) * DD + n0 + cc * 4);
    T[row][cc * 4 + 0] = v.x; T[row][cc * 4 + 1] = v.y;
    T[row][cc * 4 + 2] = v.z; T[row][cc * 4 + 3] = v.w;
  }
  __syncthreads();
#pragma unroll
  for (int i = 0; i < 2; ++i) {
    int c = t + i * 256;
    int nr = c >> 3, kc = c & 7;
    ushort4 a, b;
    a.x = f2bf(T[kc * 8 + 0][nr]); a.y = f2bf(T[kc * 8 + 1][nr]);
    a.z = f2bf(T[kc * 8 + 2][nr]); a.w = f2bf(T[kc * 8 + 3][nr]);
    b.x = f2bf(T[kc * 8 + 4][nr]); b.y = f2bf(T[kc * 8 + 5][nr]);
    b.z = f2bf(T[kc * 8 + 6][nr]); b.w = f2bf(T[kc * 8 + 7][nr]);
    *(ushort4*)(wt + (size_t)(n0 + nr) * DD + k0 + kc * 8) = a;
    *(ushort4*)(wt + (size_t)(n0 + nr) * DD + k0 + kc * 8 + 4) = b;
  }
}

// ---------------- shared MFMA GEMM body: 64x64 tile, BK=64, NT form ----------

__device__ __forceinline__ void mfma_gemm64(
    const ushort* __restrict__ A, int lda, const ushort* __restrict__ B, int ldb,
    int K, ushort (*As)[72], ushort (*Bs)[72], f32x4 (&acc)[2][2], int t) {
  const int l = t & 63, w = t >> 6;
  const int mq = w & 1, nq = w >> 1;
  const int l15 = l & 15, l4 = l >> 4;
  for (int k0 = 0; k0 < K; k0 += 64) {
    __syncthreads();
#pragma unroll
    for (int i = 0; i < 2; ++i) {
      int c = t + i * 256;
      int row = c >> 3, cc = c & 7;
      *(uint4*)&As[row][cc * 8] = *(const uint4*)(A + (size_t)row * lda + k0 + cc * 8);
      *(uint4*)&Bs[row][cc * 8] = *(const uint4*)(B + (size_t)row * ldb + k0 + cc * 8);
    }
    __syncthreads();
    short8 af[2][2], bf[2][2];
#pragma unroll
    for (int mt = 0; mt < 2; ++mt)
#pragma unroll
      for (int ks = 0; ks < 2; ++ks)
        af[mt][ks] = *(const short8*)&As[32 * mq + 16 * mt + l15][ks * 32 + l4 * 8];
#pragma unroll
    for (int nt = 0; nt < 2; ++nt)
#pragma unroll
      for (int ks = 0; ks < 2; ++ks)
        bf[nt][ks] = *(const short8*)&Bs[32 * nq + 16 * nt + l15][ks * 32 + l4 * 8];
#pragma unroll
    for (int mt = 0; mt < 2; ++mt)
#pragma unroll
      for (int nt = 0; nt < 2; ++nt)
#pragma unroll
        for (int ks = 0; ks < 2; ++ks)
          acc[mt][nt] = __builtin_amdgcn_mfma_f32_16x16x32_bf16(
              af[mt][ks], bf[nt][ks], acc[mt][nt], 0, 0, 0);
  }
}

// ---------------- QKV projection ----------------
// out: q (prescaled by 1/8), k as bf16 [z][s][dk]; v transposed bf16 [z][dk][s]

__global__ __launch_bounds__(256) void proj_qkv_kernel(
    const ushort* __restrict__ xb,
    const ushort* __restrict__ wqt, const float* __restrict__ bq,
    const ushort* __restrict__ wkt, const float* __restrict__ bk,
    const ushort* __restrict__ wvt, const float* __restrict__ bv,
    ushort* __restrict__ qb, ushort* __restrict__ kb, ushort* __restrict__ vt) {
  __shared__ ushort As[64][72], Bs[64][72];
  const ushort* W; const float* bias; ushort* out;
  if (blockIdx.z == 0) { W = wqt; bias = bq; out = qb; }
  else if (blockIdx.z == 1) { W = wkt; bias = bk; out = kb; }
  else { W = wvt; bias = bv; out = vt; }
  const float scale = (blockIdx.z == 0) ? 0.125f : 1.0f;  // fold 1/sqrt(dk) into Q
  const int m0 = blockIdx.x * 64;
  const int h = blockIdx.y;
  const int t = threadIdx.x;
  const int l = t & 63, w = t >> 6;
  const int mq = w & 1, nq = w >> 1;
  const int l15 = l & 15, l4 = l >> 4;
  f32x4 acc[2][2] = {};
  mfma_gemm64(xb + (size_t)m0 * DD, DD, W + (size_t)h * DKK * DD, DD, DD,
              As, Bs, acc, t);
  float biasv[2];
#pragma unroll
  for (int nt = 0; nt < 2; ++nt) biasv[nt] = bias[h * DKK + 32 * nq + 16 * nt + l15];

  if (blockIdx.z < 2) {
    __syncthreads();
#pragma unroll
    for (int mt = 0; mt < 2; ++mt)
#pragma unroll
      for (int nt = 0; nt < 2; ++nt)
#pragma unroll
        for (int r = 0; r < 4; ++r)
          As[32 * mq + 16 * mt + l4 * 4 + r][32 * nq + 16 * nt + l15] =
              f2bf((acc[mt][nt][r] + biasv[nt]) * scale);
    __syncthreads();
#pragma unroll
    for (int i = 0; i < 2; ++i) {
      int c = t + i * 256;
      int row = c >> 3, cc = c & 7;
      int m = m0 + row, b = m >> 11, s = m & (SS - 1);
      uint4 v = *(const uint4*)&As[row][cc * 8];
      *(uint4*)(out + ((size_t)(b * HH + h) * SS + s) * DKK + cc * 8) = v;
    }
  } else {
#pragma unroll
    for (int mt = 0; mt < 2; ++mt)
#pragma unroll
      for (int nt = 0; nt < 2; ++nt) {
        int dk = 32 * nq + 16 * nt + l15;
        int m = m0 + 32 * mq + 16 * mt + l4 * 4;
        int b = m >> 11, sb = m & (SS - 1);
        ushort4 pk;
        pk.x = f2bf(acc[mt][nt][0] + biasv[nt]);
        pk.y = f2bf(acc[mt][nt][1] + biasv[nt]);
        pk.z = f2bf(acc[mt][nt][2] + biasv[nt]);
        pk.w = f2bf(acc[mt][nt][3] + biasv[nt]);
        *(ushort4*)(out + ((size_t)(b * HH + h) * DKK + dk) * SS + sb) = pk;
      }
  }
}

// ---------------- fused attention: two phases, one kernel ----------------
// Phase 1 (swapped mfma(K,Q): LDS-only P stores, layout irrelevant to HBM):
//   K,V staged; p=exp(score+bias) unnormalized; rowsum in regs; P->LDS bf16;
//   PV accumulate. NO global P traffic.
// Then: rowsum reduce; ctx tile written (oacc * 1/rowsum).
// Phase 2 (NON-swapped mfma(Q,K): coalesced attn stores):
//   acc[mt][nt][r] = P[qi=..+l4*4+r][kj=..+l15] -> 16 consecutive lanes write
//   16 consecutive kj dwords (256B/wave-instr contiguous). K double-buffered.
// Grid dim3(32,16): qtile fastest -> consecutive blocks share z (K/V L2 reuse).

__global__ __launch_bounds__(256) void attn_kernel(
    const ushort* __restrict__ qb, const ushort* __restrict__ kb,
    const ushort* __restrict__ vt, float* __restrict__ attn,
    ushort* __restrict__ ctx) {
  __shared__ ushort Ks[64][72], Vs[64][72], Ps[64][72];
  __shared__ float rs[64];
  const int t = threadIdx.x;
  const int l = t & 63, w = t >> 6;
  const int mq = w & 1, nq = w >> 1;
  const int l15 = l & 15, l4 = l >> 4;
  const int z = blockIdx.y;
  const int q0 = blockIdx.x * 64;
  if (t < 64) rs[t] = 0.f;

  // Q fragments (already prescaled by 1/8) in registers.
  // Same per-lane layout serves as A- or B-operand fragment.
  short8 qf[2][2];
#pragma unroll
  for (int bt = 0; bt < 2; ++bt)
#pragma unroll
    for (int ks = 0; ks < 2; ++ks)
      qf[bt][ks] = *(const short8*)(qb +
          ((size_t)z * SS + q0 + 32 * mq + 16 * bt + l15) * DKK + ks * 32 + l4 * 8);

  int qi_[2]; float rowf[2];
#pragma unroll
  for (int bt = 0; bt < 2; ++bt) {
    qi_[bt] = q0 + 32 * mq + 16 * bt + l15;
    rowf[bt] = __expf(-0.02f * (float)qi_[bt]);
  }
  const float c_r[4] = {1.0f, 1.0202013f, 1.0408108f, 1.0618365f};  // exp(0.02 r)

  float rsp[2] = {0.f, 0.f};
  f32x4 oacc[2][2] = {};

  // ---- phase 1: rowsums + PV (no global P stores) ----
  for (int kt = 0; kt < 32; ++kt) {
    __syncthreads();
#pragma unroll
    for (int i = 0; i < 2; ++i) {
      int c = t + i * 256;
      int row = c >> 3, cc = c & 7;
      *(uint4*)&Ks[row][cc * 8] =
          *(const uint4*)(kb + ((size_t)z * SS + kt * 64 + row) * DKK + cc * 8);
      *(uint4*)&Vs[row][cc * 8] =
          *(const uint4*)(vt + ((size_t)z * DKK + row) * SS + kt * 64 + cc * 8);
    }
    __syncthreads();
    short8 kf[2][2];
#pragma unroll
    for (int at = 0; at < 2; ++at)
#pragma unroll
      for (int ks = 0; ks < 2; ++ks)
        kf[at][ks] = *(const short8*)&Ks[32 * nq + 16 * at + l15][ks * 32 + l4 * 8];
    f32x4 acc[2][2] = {};
#pragma unroll
    for (int at = 0; at < 2; ++at)
#pragma unroll
      for (int bt = 0; bt < 2; ++bt)
#pragma unroll
        for (int ks = 0; ks < 2; ++ks)
          acc[at][bt] = __builtin_amdgcn_mfma_f32_16x16x32_bf16(
              kf[at][ks], qf[bt][ks], acc[at][bt], 0, 0, 0);
#pragma unroll
    for (int at = 0; at < 2; ++at) {
      const int kjbase = kt * 64 + 32 * nq + 16 * at + l4 * 4;
      const float colb = __expf(0.02f * (float)kjbase);
#pragma unroll
      for (int bt = 0; bt < 2; ++bt) {
        const float rc = rowf[bt] * colb;
        ushort4 us;
        float pv[4];
#pragma unroll
        for (int r = 0; r < 4; ++r) {
          float bias = (kjbase + r <= qi_[bt]) ? rc * c_r[r] : 0.f;
          float p = __expf(acc[at][bt][r] + bias);
          pv[r] = p;
          rsp[bt] += p;
        }
        us.x = f2bf(pv[0]); us.y = f2bf(pv[1]);
        us.z = f2bf(pv[2]); us.w = f2bf(pv[3]);
        *(ushort4*)&Ps[32 * mq + 16 * bt + l15][32 * nq + 16 * at + l4 * 4] = us;
      }
    }
    __syncthreads();   // Ps ready
    short8 pa[2][2], pb[2][2];
#pragma unroll
    for (int mt = 0; mt < 2; ++mt)
#pragma unroll
      for (int ks = 0; ks < 2; ++ks)
        pa[mt][ks] = *(const short8*)&Ps[32 * mq + 16 * mt + l15][ks * 32 + l4 * 8];
#pragma unroll
    for (int nt = 0; nt < 2; ++nt)
#pragma unroll
      for (int ks = 0; ks < 2; ++ks)
        pb[nt][ks] = *(const short8*)&Vs[32 * nq + 16 * nt + l15][ks * 32 + l4 * 8];
#pragma unroll
    for (int mt = 0; mt < 2; ++mt)
#pragma unroll
      for (int nt = 0; nt < 2; ++nt)
#pragma unroll
        for (int ks = 0; ks < 2; ++ks)
          oacc[mt][nt] = __builtin_amdgcn_mfma_f32_16x16x32_bf16(
              pa[mt][ks], pb[nt][ks], oacc[mt][nt], 0, 0, 0);
  }

  // rowsum reduce: lanes sharing qi differ in l4 (xor 16,32) x 2 waves (nq)
#pragma unroll
  for (int bt = 0; bt < 2; ++bt) {
    float v = rsp[bt];
    v += __shfl_xor(v, 16);
    v += __shfl_xor(v, 32);
    if (l < 16) atomicAdd(&rs[32 * mq + 16 * bt + l], v);
  }
  __syncthreads();
  // normalizers + bias row factors for phase-2 row mapping (qi = ..+l4*4+r)
  float invr[2][4], rowf2[2][4]; int qi2_[2][4];
#pragma unroll
  for (int mt = 0; mt < 2; ++mt)
#pragma unroll
    for (int r = 0; r < 4; ++r) {
      int qi2 = q0 + 32 * mq + 16 * mt + l4 * 4 + r;
      qi2_[mt][r] = qi2;
      rowf2[mt][r] = __expf(-0.02f * (float)qi2);
      invr[mt][r] = 1.f / rs[32 * mq + 16 * mt + l4 * 4 + r];
    }

  // ctx epilogue via LDS bounce (Ps reuse; all PV reads done: synced above)
#pragma unroll
  for (int mt = 0; mt < 2; ++mt)
#pragma unroll
    for (int nt = 0; nt < 2; ++nt)
#pragma unroll
      for (int r = 0; r < 4; ++r)
        Ps[32 * mq + 16 * mt + l4 * 4 + r][32 * nq + 16 * nt + l15] =
            f2bf(oacc[mt][nt][r] * invr[mt][r]);
  __syncthreads();
  {
    const int b = z >> 3, h = z & 7;
#pragma unroll
    for (int i = 0; i < 2; ++i) {
      int c = t + i * 256;
      int row = c >> 3, cc = c & 7;
      uint4 v = *(const uint4*)&Ps[row][cc * 8];
      *(uint4*)(ctx + ((size_t)(b * SS + q0 + row)) * DD + h * DKK + cc * 8) = v;
    }
  }

  // ---- phase 2: recompute QK^T (non-swapped), write normalized fp32 attn ----
  // K double-buffered in Ks (even kt) / Vs (odd kt): 1 barrier per iter.
  const int srow = t >> 3, scol = (t & 7) * 8;   // staging: 2 rows/thread
  const int srow2 = srow + 32;
  __syncthreads();   // ctx LDS reads complete before any buffer reuse
  {
    const ushort* p = kb + (size_t)z * SS * DKK;
    *(uint4*)&Ks[srow][scol]  = *(const uint4*)(p + (size_t)srow * DKK + scol);
    *(uint4*)&Ks[srow2][scol] = *(const uint4*)(p + (size_t)srow2 * DKK + scol);
  }
  __syncthreads();
  for (int kt = 0; kt < 32; ++kt) {
    ushort (*cur)[72] = (kt & 1) ? Vs : Ks;
    ushort (*nxt)[72] = (kt & 1) ? Ks : Vs;
    uint4 s0, s1;
    if (kt < 31) {
      const ushort* p = kb + ((size_t)z * SS + (kt + 1) * 64) * DKK;
      s0 = *(const uint4*)(p + (size_t)srow * DKK + scol);
      s1 = *(const uint4*)(p + (size_t)srow2 * DKK + scol);
    }
    short8 kf[2][2];
#pragma unroll
    for (int nt = 0; nt < 2; ++nt)
#pragma unroll
      for (int ks = 0; ks < 2; ++ks)
        kf[nt][ks] = *(const short8*)&cur[32 * nq + 16 * nt + l15][ks * 32 + l4 * 8];
    f32x4 acc[2][2] = {};
#pragma unroll
    for (int mt = 0; mt < 2; ++mt)
#pragma unroll
      for (int nt = 0; nt < 2; ++nt)
#pragma unroll
        for (int ks = 0; ks < 2; ++ks)
          acc[mt][nt] = __builtin_amdgcn_mfma_f32_16x16x32_bf16(
              qf[mt][ks], kf[nt][ks], acc[mt][nt], 0, 0, 0);
#pragma unroll
    for (int nt = 0; nt < 2; ++nt) {
      const int kj = kt * 64 + 32 * nq + 16 * nt + l15;
      const float colf = __expf(0.02f * (float)kj);
#pragma unroll
      for (int mt = 0; mt < 2; ++mt) {
        const size_t rbase = ((size_t)z * SS + qi2_[mt][0]) * SS + kj;
#pragma unroll
        for (int r = 0; r < 4; ++r) {
          float bias = (kj <= qi2_[mt][r]) ? rowf2[mt][r] * colf : 0.f;
          float p = __expf(acc[mt][nt][r] + bias) * invr[mt][r];
          attn[rbase + (size_t)r * SS] = p;
        }
      }
    }
    if (kt < 31) {
      *(uint4*)&nxt[srow][scol]  = s0;
      *(uint4*)&nxt[srow2][scol] = s1;
    }
    __syncthreads();
  }
}

// ---------------- O projection ----------------

__global__ __launch_bounds__(256) void proj_o_kernel(
    const ushort* __restrict__ ctx, const ushort* __restrict__ wot,
    const float* __restrict__ bo, float* __restrict__ o) {
  __shared__ ushort As[64][72], Bs[64][72];
  const int m0 = blockIdx.x * 64, n0 = blockIdx.y * 64;
  const int t = threadIdx.x;
  const int l = t & 63, w = t >> 6;
  const int mq = w & 1, nq = w >> 1;
  const int l15 = l & 15, l4 = l >> 4;
  f32x4 acc[2][2] = {};
  mfma_gemm64(ctx + (size_t)m0 * DD, DD, wot + (size_t)n0 * DD, DD, DD,
              As, Bs, acc, t);
#pragma unroll
  for (int nt = 0; nt < 2; ++nt) {
    int col = n0 + 32 * nq + 16 * nt + l15;
    float bv = bo[col];
#pragma unroll
    for (int mt = 0; mt < 2; ++mt)
#pragma unroll
      for (int r = 0; r < 4; ++r) {
        int m = m0 + 32 * mq + 16 * mt + l4 * 4 + r;
        o[(size_t)m * DD + col] = acc[mt][nt][r] + bv;
      }
  }
}

// ---------------- gate MLP (fp32, small) ----------------

__global__ __launch_bounds__(256) void gate_kernel(
    const float* __restrict__ x, const float* __restrict__ g1w,
    const float* __restrict__ g1b, const float* __restrict__ g2w,
    const float* __restrict__ g2b, float* __restrict__ gate) {
  __shared__ float xs[8][512];
  __shared__ float red[32];
  const int r0 = blockIdx.x * 8;
  const int t = threadIdx.x;
  const float4* xg = (const float4*)&x[(size_t)r0 * DD];
  float4* xsv = (float4*)&xs[0][0];
#pragma unroll
  for (int i = 0; i < 4; ++i) xsv[t + i * 256] = xg[t + i * 256];
  __syncthreads();
  float acc[8] = {};
  for (int i = 0; i < 512; i += 4) {
    float w0 = g1w[(i + 0) * 256 + t];
    float w1 = g1w[(i + 1) * 256 + t];
    float w2 = g1w[(i + 2) * 256 + t];
    float w3 = g1w[(i + 3) * 256 + t];
#pragma unroll
    for (int r = 0; r < 8; ++r) {
      float4 xv = *(const float4*)&xs[r][i];
      acc[r] += xv.x * w0 + xv.y * w1 + xv.z * w2 + xv.w * w3;
    }
  }
  float b1 = g1b[t], w2_ = g2w[t];
  float p[8];
#pragma unroll
  for (int r = 0; r < 8; ++r) {
    float h = acc[r] + b1;
    h = h > 0.f ? h : 0.f;
    p[r] = h * w2_;
  }
#pragma unroll
  for (int r = 0; r < 8; ++r)
    for (int off = 32; off; off >>= 1) p[r] += __shfl_xor(p[r], off, 64);
  if ((t & 63) == 0) {
#pragma unroll
    for (int r = 0; r < 8; ++r) red[r * 4 + (t >> 6)] = p[r];
  }
  __syncthreads();
  if (t < 8) {
    float s = red[t * 4] + red[t * 4 + 1] + red[t * 4 + 2] + red[t * 4 + 3] + g2b[0];
    gate[r0 + t] = 1.f / (1.f + __expf(-s));
  }
}

// ---------------- gated blend + layernorm ----------------

__global__ __launch_bounds__(256) void blend_ln_kernel(
    const float* __restrict__ o, const float* __restrict__ x,
    const float* __restrict__ gate, const float* __restrict__ ln_g,
    const float* __restrict__ ln_b, float* __restrict__ y) {
  __shared__ float r1[4], r2[4];
  const int row = blockIdx.x, t = threadIdx.x;
  float g = gate[row];
  float2 o2 = *(const float2*)&o[(size_t)row * DD + t * 2];
  float2 x2 = *(const float2*)&x[(size_t)row * DD + t * 2];
  float va = o2.x * g + x2.x * (1.f - g);
  float vb = o2.y * g + x2.y * (1.f - g);
  float s = va + vb, q = va * va + vb * vb;
  for (int off = 32; off; off >>= 1) {
    s += __shfl_xor(s, off, 64);
    q += __shfl_xor(q, off, 64);
  }
  if ((t & 63) == 0) { r1[t >> 6] = s; r2[t >> 6] = q; }
  __syncthreads();
  s = r1[0] + r1[1] + r1[2] + r1[3];
  q = r2[0] + r2[1] + r2[2] + r2[3];
  float mean = s * (1.f / 512.f);
  float var = q * (1.f / 512.f) - mean * mean;
  float rstd = rsqrtf(var + 1e-5f);
  float2 lg = *(const float2*)&ln_g[t * 2];
  float2 lb = *(const float2*)&ln_b[t * 2];
  float2 out;
  out.x = (va - mean) * rstd * lg.x + lb.x;
  out.y = (vb - mean) * rstd * lg.y + lb.y;
  *(float2*)&y[(size_t)row * DD + t * 2] = out;
}

extern "C" void kernel_launch(void* const* d_in, const int* in_sizes, int n_in,
                              void* d_out, int out_size, void* d_ws, size_t ws_size,
                              hipStream_t stream) {
  const float* x   = (const float*)d_in[0];
  const float* wq  = (const float*)d_in[1];
  const float* bq  = (const float*)d_in[2];
  const float* wk  = (const float*)d_in[3];
  const float* bk  = (const float*)d_in[4];
  const float* wv  = (const float*)d_in[5];
  const float* bv  = (const float*)d_in[6];
  const float* wo  = (const float*)d_in[7];
  const float* bo  = (const float*)d_in[8];
  const float* g1w = (const float*)d_in[9];
  const float* g1b = (const float*)d_in[10];
  const float* g2w = (const float*)d_in[11];
  const float* g2b = (const float*)d_in[12];
  const float* lng = (const float*)d_in[13];
  const float* lnb = (const float*)d_in[14];

  float* y    = (float*)d_out;
  float* attn = y + (size_t)Y_SIZE;

  char* ws = (char*)d_ws;
  ushort* xb  = (ushort*)(ws);                       // 4 MB
  ushort* wqt = (ushort*)(ws + (4 << 20));           // 512 KB
  ushort* wkt = (ushort*)(ws + (4 << 20) + (512 << 10));
  ushort* wvt = (ushort*)(ws + (5 << 20));
  ushort* wot = (ushort*)(ws + (5 << 20) + (512 << 10));
  ushort* qb  = (ushort*)(ws + (6 << 20));           // 4 MB
  ushort* kb  = (ushort*)(ws + (10 << 20));          // 4 MB
  ushort* vt  = (ushort*)(ws + (14 << 20));          // 4 MB
  ushort* ctx = (ushort*)(ws + (18 << 20));          // 4 MB
  float*  o   = (float*)(ws + (22 << 20));           // 8 MB
  float*  gate= (float*)(ws + (30 << 20));           // 16 KB

  hipLaunchKernelGGL(conv_x_kernel, dim3(Y_SIZE / 1024), dim3(256), 0, stream, x, xb);
  hipLaunchKernelGGL(conv_wt_kernel, dim3(8, 8, 4), dim3(256), 0, stream,
                     wq, wk, wv, wo, wqt, wkt, wvt, wot);
  hipLaunchKernelGGL(proj_qkv_kernel, dim3(64, 8, 3), dim3(256), 0, stream,
                     xb, wqt, bq, wkt, bk, wvt, bv, qb, kb, vt);
  hipLaunchKernelGGL(gate_kernel, dim3(512), dim3(256), 0, stream,
                     x, g1w, g1b, g2w, g2b, gate);
  hipLaunchKernelGGL(attn_kernel, dim3(32, 16), dim3(256), 0, stream,
                     qb, kb, vt, attn, ctx);
  hipLaunchKernelGGL(proj_o_kernel, dim3(64, 8), dim3(256), 0, stream,
                     ctx, wot, bo, o);
  hipLaunchKernelGGL(blend_ln_kernel, dim3(4096), dim3(256), 0, stream,
                     o, x, gate, lng, lnb, y);
}

// Round 5
// 426.502 us; speedup vs baseline: 1.1627x; 1.0744x over previous
//
#include <hip/hip_runtime.h>

#define BB 2
#define SS 2048
#define DD 512
#define HH 8
#define DKK 64
#define NROWS (BB * SS)          // 4096
#define Y_SIZE (BB * SS * DD)    // 2097152

typedef __attribute__((ext_vector_type(8))) short short8;
typedef __attribute__((ext_vector_type(4))) float f32x4;

__device__ __forceinline__ ushort f2bf(float f) {
  union { float f; unsigned u; } v; v.f = f;
  unsigned u = v.u;
  return (ushort)((u + 0x7fffu + ((u >> 16) & 1u)) >> 16);
}

// ---------------- converts ----------------

__global__ __launch_bounds__(256) void conv_x_kernel(const float* __restrict__ x,
                                                     ushort* __restrict__ xb) {
  int i = (blockIdx.x * 256 + threadIdx.x) * 4;
  float4 v = *(const float4*)(x + i);
  ushort4 o = {f2bf(v.x), f2bf(v.y), f2bf(v.z), f2bf(v.w)};
  *(ushort4*)(xb + i) = o;
}

// transpose 512x512 fp32 w[k][n] -> bf16 wt[n][k]
__global__ __launch_bounds__(256) void conv_wt_kernel(
    const float* __restrict__ w0, const float* __restrict__ w1,
    const float* __restrict__ w2, const float* __restrict__ w3,
    ushort* __restrict__ o0, ushort* __restrict__ o1,
    ushort* __restrict__ o2, ushort* __restrict__ o3) {
  __shared__ float T[64][65];
  const float* w; ushort* wt;
  switch (blockIdx.z) {
    case 0: w = w0; wt = o0; break;
    case 1: w = w1; wt = o1; break;
    case 2: w = w2; wt = o2; break;
    default: w = w3; wt = o3; break;
  }
  const int t = threadIdx.x;
  const int n0 = blockIdx.x * 64, k0 = blockIdx.y * 64;
#pragma unroll
  for (int i = 0; i < 4; ++i) {
    int c = t + i * 256;
    int row = c >> 4, cc = c & 15;
    float4 v = *(const float4*)(w + (size_t)(k0 + row) * DD + n0 + cc * 4);
    T[row][cc * 4 + 0] = v.x; T[row][cc * 4 + 1] = v.y;
    T[row][cc * 4 + 2] = v.z; T[row][cc * 4 + 3] = v.w;
  }
  __syncthreads();
#pragma unroll
  for (int i = 0; i < 2; ++i) {
    int c = t + i * 256;
    int nr = c >> 3, kc = c & 7;
    ushort4 a, b;
    a.x = f2bf(T[kc * 8 + 0][nr]); a.y = f2bf(T[kc * 8 + 1][nr]);
    a.z = f2bf(T[kc * 8 + 2][nr]); a.w = f2bf(T[kc * 8 + 3][nr]);
    b.x = f2bf(T[kc * 8 + 4][nr]); b.y = f2bf(T[kc * 8 + 5][nr]);
    b.z = f2bf(T[kc * 8 + 6][nr]); b.w = f2bf(T[kc * 8 + 7][nr]);
    *(ushort4*)(wt + (size_t)(n0 + nr) * DD + k0 + kc * 8) = a;
    *(ushort4*)(wt + (size_t)(n0 + nr) * DD + k0 + kc * 8 + 4) = b;
  }
}

// ---------------- shared MFMA GEMM body: 64x64 tile, BK=64, NT form ----------

__device__ __forceinline__ void mfma_gemm64(
    const ushort* __restrict__ A, int lda, const ushort* __restrict__ B, int ldb,
    int K, ushort (*As)[72], ushort (*Bs)[72], f32x4 (&acc)[2][2], int t) {
  const int l = t & 63, w = t >> 6;
  const int mq = w & 1, nq = w >> 1;
  const int l15 = l & 15, l4 = l >> 4;
  for (int k0 = 0; k0 < K; k0 += 64) {
    __syncthreads();
#pragma unroll
    for (int i = 0; i < 2; ++i) {
      int c = t + i * 256;
      int row = c >> 3, cc = c & 7;
      *(uint4*)&As[row][cc * 8] = *(const uint4*)(A + (size_t)row * lda + k0 + cc * 8);
      *(uint4*)&Bs[row][cc * 8] = *(const uint4*)(B + (size_t)row * ldb + k0 + cc * 8);
    }
    __syncthreads();
    short8 af[2][2], bf[2][2];
#pragma unroll
    for (int mt = 0; mt < 2; ++mt)
#pragma unroll
      for (int ks = 0; ks < 2; ++ks)
        af[mt][ks] = *(const short8*)&As[32 * mq + 16 * mt + l15][ks * 32 + l4 * 8];
#pragma unroll
    for (int nt = 0; nt < 2; ++nt)
#pragma unroll
      for (int ks = 0; ks < 2; ++ks)
        bf[nt][ks] = *(const short8*)&Bs[32 * nq + 16 * nt + l15][ks * 32 + l4 * 8];
#pragma unroll
    for (int mt = 0; mt < 2; ++mt)
#pragma unroll
      for (int nt = 0; nt < 2; ++nt)
#pragma unroll
        for (int ks = 0; ks < 2; ++ks)
          acc[mt][nt] = __builtin_amdgcn_mfma_f32_16x16x32_bf16(
              af[mt][ks], bf[nt][ks], acc[mt][nt], 0, 0, 0);
  }
}

// ---------------- QKV projection ----------------
// out: q (prescaled by log2e/8), k as bf16 [z][s][dk]; v transposed [z][dk][s]

__global__ __launch_bounds__(256) void proj_qkv_kernel(
    const ushort* __restrict__ xb,
    const ushort* __restrict__ wqt, const float* __restrict__ bq,
    const ushort* __restrict__ wkt, const float* __restrict__ bk,
    const ushort* __restrict__ wvt, const float* __restrict__ bv,
    ushort* __restrict__ qb, ushort* __restrict__ kb, ushort* __restrict__ vt) {
  __shared__ ushort As[64][72], Bs[64][72];
  const ushort* W; const float* bias; ushort* out;
  if (blockIdx.z == 0) { W = wqt; bias = bq; out = qb; }
  else if (blockIdx.z == 1) { W = wkt; bias = bk; out = kb; }
  else { W = wvt; bias = bv; out = vt; }
  // fold 1/sqrt(dk) AND log2(e) into Q so attn uses exp2 (one v_mul less/exp)
  const float scale = (blockIdx.z == 0) ? 0.1803368801f : 1.0f;
  const int m0 = blockIdx.x * 64;
  const int h = blockIdx.y;
  const int t = threadIdx.x;
  const int l = t & 63, w = t >> 6;
  const int mq = w & 1, nq = w >> 1;
  const int l15 = l & 15, l4 = l >> 4;
  f32x4 acc[2][2] = {};
  mfma_gemm64(xb + (size_t)m0 * DD, DD, W + (size_t)h * DKK * DD, DD, DD,
              As, Bs, acc, t);
  float biasv[2];
#pragma unroll
  for (int nt = 0; nt < 2; ++nt) biasv[nt] = bias[h * DKK + 32 * nq + 16 * nt + l15];

  if (blockIdx.z < 2) {
    __syncthreads();
#pragma unroll
    for (int mt = 0; mt < 2; ++mt)
#pragma unroll
      for (int nt = 0; nt < 2; ++nt)
#pragma unroll
        for (int r = 0; r < 4; ++r)
          As[32 * mq + 16 * mt + l4 * 4 + r][32 * nq + 16 * nt + l15] =
              f2bf((acc[mt][nt][r] + biasv[nt]) * scale);
    __syncthreads();
#pragma unroll
    for (int i = 0; i < 2; ++i) {
      int c = t + i * 256;
      int row = c >> 3, cc = c & 7;
      int m = m0 + row, b = m >> 11, s = m & (SS - 1);
      uint4 v = *(const uint4*)&As[row][cc * 8];
      *(uint4*)(out + ((size_t)(b * HH + h) * SS + s) * DKK + cc * 8) = v;
    }
  } else {
#pragma unroll
    for (int mt = 0; mt < 2; ++mt)
#pragma unroll
      for (int nt = 0; nt < 2; ++nt) {
        int dk = 32 * nq + 16 * nt + l15;
        int m = m0 + 32 * mq + 16 * mt + l4 * 4;
        int b = m >> 11, sb = m & (SS - 1);
        ushort4 pk;
        pk.x = f2bf(acc[mt][nt][0] + biasv[nt]);
        pk.y = f2bf(acc[mt][nt][1] + biasv[nt]);
        pk.z = f2bf(acc[mt][nt][2] + biasv[nt]);
        pk.w = f2bf(acc[mt][nt][3] + biasv[nt]);
        *(ushort4*)(out + ((size_t)(b * HH + h) * DKK + dk) * SS + sb) = pk;
      }
  }
}

// ---------------- fused attention: two phases, one kernel ----------------
// OCCUPANCY build: 32 q-rows/block, grid (64,16) = 1024 blocks = 4 blocks/CU
// (16 waves/CU) so barrier/load stalls of one block are hidden by 3 others.
// 4 waves each own one 16-kj quad (nq = wave id).
// Phase 1 (swapped mfma(K,Q)): K,V staged; p=exp2(score2+bias2) unnormalized
//   (log2e folded into Q prescale and rowf); rowsum in regs; P->LDS bf16; PV.
// Phase 2 (non-swapped mfma(Q,K)): K double-buffered, 1 barrier/iter,
//   normalized fp32 attn stores, l15 sweeps 16 consecutive kj (coalesced).

__global__ __launch_bounds__(256, 4) void attn_kernel(
    const ushort* __restrict__ qb, const ushort* __restrict__ kb,
    const ushort* __restrict__ vt, float* __restrict__ attn,
    ushort* __restrict__ ctx) {
  __shared__ ushort Ks[64][72], Vs[64][72], Ps[32][72];
  __shared__ float rs[32];
  const int t = threadIdx.x;
  const int l = t & 63, nq = t >> 6;      // wave id = kj/d quad
  const int l15 = l & 15, l4 = l >> 4;
  const int z = blockIdx.y;
  const int q0 = blockIdx.x * 32;
  if (t < 32) rs[t] = 0.f;

  // Q fragments (prescaled by log2e/8) in registers; layout serves A or B.
  short8 qf[2][2];
#pragma unroll
  for (int bt = 0; bt < 2; ++bt)
#pragma unroll
    for (int ks = 0; ks < 2; ++ks)
      qf[bt][ks] = *(const short8*)(qb +
          ((size_t)z * SS + q0 + 16 * bt + l15) * DKK + ks * 32 + l4 * 8);

  const float LOG2E = 1.4426950409f;
  int qi_[2]; float rowf[2];
#pragma unroll
  for (int bt = 0; bt < 2; ++bt) {
    qi_[bt] = q0 + 16 * bt + l15;
    rowf[bt] = LOG2E * __expf(-0.02f * (float)qi_[bt]);
  }
  const float c_r[4] = {1.0f, 1.0202013f, 1.0408108f, 1.0618365f};  // exp(0.02 r)

  float rsp[2] = {0.f, 0.f};
  f32x4 oacc[2] = {};

  // ---- phase 1: rowsums + PV (no global P traffic) ----
  for (int kt = 0; kt < 32; ++kt) {
    __syncthreads();
#pragma unroll
    for (int i = 0; i < 2; ++i) {
      int c = t + i * 256;
      int row = c >> 3, cc = c & 7;
      *(uint4*)&Ks[row][cc * 8] =
          *(const uint4*)(kb + ((size_t)z * SS + kt * 64 + row) * DKK + cc * 8);
      *(uint4*)&Vs[row][cc * 8] =
          *(const uint4*)(vt + ((size_t)z * DKK + row) * SS + kt * 64 + cc * 8);
    }
    __syncthreads();
    // swapped QK^T: A = K rows (wave's 16-kj quad), B = Q
    short8 kf[2];
#pragma unroll
    for (int ks = 0; ks < 2; ++ks)
      kf[ks] = *(const short8*)&Ks[16 * nq + l15][ks * 32 + l4 * 8];
    f32x4 acc[2] = {};
#pragma unroll
    for (int bt = 0; bt < 2; ++bt)
#pragma unroll
      for (int ks = 0; ks < 2; ++ks)
        acc[bt] = __builtin_amdgcn_mfma_f32_16x16x32_bf16(
            kf[ks], qf[bt][ks], acc[bt], 0, 0, 0);
    // epilogue: 8 elems/lane
    {
      const int kjbase = kt * 64 + 16 * nq + l4 * 4;
      const float colb = __expf(0.02f * (float)kjbase);
#pragma unroll
      for (int bt = 0; bt < 2; ++bt) {
        const float rc = rowf[bt] * colb;
        ushort4 us;
        float pv[4];
#pragma unroll
        for (int r = 0; r < 4; ++r) {
          float bias = (kjbase + r <= qi_[bt]) ? rc * c_r[r] : 0.f;
          float p = exp2f(acc[bt][r] + bias);
          pv[r] = p;
          rsp[bt] += p;
        }
        us.x = f2bf(pv[0]); us.y = f2bf(pv[1]);
        us.z = f2bf(pv[2]); us.w = f2bf(pv[3]);
        *(ushort4*)&Ps[16 * bt + l15][16 * nq + l4 * 4] = us;
      }
    }
    __syncthreads();   // Ps ready
    // PV: A = P rows (2 q-tiles), B = V^T rows (wave's 16-d quad)
    short8 pa[2][2], pb[2];
#pragma unroll
    for (int mt = 0; mt < 2; ++mt)
#pragma unroll
      for (int ks = 0; ks < 2; ++ks)
        pa[mt][ks] = *(const short8*)&Ps[16 * mt + l15][ks * 32 + l4 * 8];
#pragma unroll
    for (int ks = 0; ks < 2; ++ks)
      pb[ks] = *(const short8*)&Vs[16 * nq + l15][ks * 32 + l4 * 8];
#pragma unroll
    for (int mt = 0; mt < 2; ++mt)
#pragma unroll
      for (int ks = 0; ks < 2; ++ks)
        oacc[mt] = __builtin_amdgcn_mfma_f32_16x16x32_bf16(
            pa[mt][ks], pb[ks], oacc[mt], 0, 0, 0);
  }

  // rowsum reduce: combine l4 groups (xor 16,32), then across 4 waves via LDS
#pragma unroll
  for (int bt = 0; bt < 2; ++bt) {
    float v = rsp[bt];
    v += __shfl_xor(v, 16);
    v += __shfl_xor(v, 32);
    if (l < 16) atomicAdd(&rs[16 * bt + l], v);
  }
  __syncthreads();
  // normalizers + phase-2 row factors (rows qi = q0 + 16mt + l4*4 + r)
  float invr[2][4], rowf2[2][4]; int qi2_[2][4];
#pragma unroll
  for (int mt = 0; mt < 2; ++mt)
#pragma unroll
    for (int r = 0; r < 4; ++r) {
      int qi2 = q0 + 16 * mt + l4 * 4 + r;
      qi2_[mt][r] = qi2;
      rowf2[mt][r] = LOG2E * __expf(-0.02f * (float)qi2);
      invr[mt][r] = 1.f / rs[16 * mt + l4 * 4 + r];
    }

  // ctx epilogue via LDS bounce (Ps reuse; PV reads done: synced above)
#pragma unroll
  for (int mt = 0; mt < 2; ++mt)
#pragma unroll
    for (int r = 0; r < 4; ++r)
      Ps[16 * mt + l4 * 4 + r][16 * nq + l15] = f2bf(oacc[mt][r] * invr[mt][r]);
  __syncthreads();
  {
    const int b = z >> 3, h = z & 7;
    const int row = t >> 3, cc = t & 7;
    *(uint4*)(ctx + ((size_t)(b * SS + q0 + row)) * DD + h * DKK + cc * 8) =
        *(const uint4*)&Ps[row][cc * 8];
  }

  // ---- phase 2: recompute QK^T (non-swapped), write normalized fp32 attn ----
  const int srow = t >> 3, scol = (t & 7) * 8;   // staging: 2 rows/thread
  const int srow2 = srow + 32;
  __syncthreads();   // ctx LDS reads complete before buffer reuse
  {
    const ushort* p = kb + (size_t)z * SS * DKK;
    *(uint4*)&Ks[srow][scol]  = *(const uint4*)(p + (size_t)srow * DKK + scol);
    *(uint4*)&Ks[srow2][scol] = *(const uint4*)(p + (size_t)srow2 * DKK + scol);
  }
  __syncthreads();
  for (int kt = 0; kt < 32; ++kt) {
    ushort (*cur)[72] = (kt & 1) ? Vs : Ks;
    ushort (*nxt)[72] = (kt & 1) ? Ks : Vs;
    uint4 s0, s1;
    if (kt < 31) {
      const ushort* p = kb + ((size_t)z * SS + (kt + 1) * 64) * DKK;
      s0 = *(const uint4*)(p + (size_t)srow * DKK + scol);
      s1 = *(const uint4*)(p + (size_t)srow2 * DKK + scol);
    }
    short8 kf[2];
#pragma unroll
    for (int ks = 0; ks < 2; ++ks)
      kf[ks] = *(const short8*)&cur[16 * nq + l15][ks * 32 + l4 * 8];
    f32x4 acc[2] = {};
#pragma unroll
    for (int mt = 0; mt < 2; ++mt)
#pragma unroll
      for (int ks = 0; ks < 2; ++ks)
        acc[mt] = __builtin_amdgcn_mfma_f32_16x16x32_bf16(
            qf[mt][ks], kf[ks], acc[mt], 0, 0, 0);
    {
      const int kj = kt * 64 + 16 * nq + l15;
      const float colf = __expf(0.02f * (float)kj);
#pragma unroll
      for (int mt = 0; mt < 2; ++mt) {
        const size_t rbase = ((size_t)z * SS + qi2_[mt][0]) * SS + kj;
#pragma unroll
        for (int r = 0; r < 4; ++r) {
          float bias = (kj <= qi2_[mt][r]) ? rowf2[mt][r] * colf : 0.f;
          float p = exp2f(acc[mt][r] + bias) * invr[mt][r];
          attn[rbase + (size_t)r * SS] = p;
        }
      }
    }
    if (kt < 31) {
      *(uint4*)&nxt[srow][scol]  = s0;
      *(uint4*)&nxt[srow2][scol] = s1;
    }
    __syncthreads();
  }
}

// ---------------- O projection ----------------

__global__ __launch_bounds__(256) void proj_o_kernel(
    const ushort* __restrict__ ctx, const ushort* __restrict__ wot,
    const float* __restrict__ bo, float* __restrict__ o) {
  __shared__ ushort As[64][72], Bs[64][72];
  const int m0 = blockIdx.x * 64, n0 = blockIdx.y * 64;
  const int t = threadIdx.x;
  const int l = t & 63, w = t >> 6;
  const int mq = w & 1, nq = w >> 1;
  const int l15 = l & 15, l4 = l >> 4;
  f32x4 acc[2][2] = {};
  mfma_gemm64(ctx + (size_t)m0 * DD, DD, wot + (size_t)n0 * DD, DD, DD,
              As, Bs, acc, t);
#pragma unroll
  for (int nt = 0; nt < 2; ++nt) {
    int col = n0 + 32 * nq + 16 * nt + l15;
    float bv = bo[col];
#pragma unroll
    for (int mt = 0; mt < 2; ++mt)
#pragma unroll
      for (int r = 0; r < 4; ++r) {
        int m = m0 + 32 * mq + 16 * mt + l4 * 4 + r;
        o[(size_t)m * DD + col] = acc[mt][nt][r] + bv;
      }
  }
}

// ---------------- gate MLP (fp32, small) ----------------

__global__ __launch_bounds__(256) void gate_kernel(
    const float* __restrict__ x, const float* __restrict__ g1w,
    const float* __restrict__ g1b, const float* __restrict__ g2w,
    const float* __restrict__ g2b, float* __restrict__ gate) {
  __shared__ float xs[8][512];
  __shared__ float red[32];
  const int r0 = blockIdx.x * 8;
  const int t = threadIdx.x;
  const float4* xg = (const float4*)&x[(size_t)r0 * DD];
  float4* xsv = (float4*)&xs[0][0];
#pragma unroll
  for (int i = 0; i < 4; ++i) xsv[t + i * 256] = xg[t + i * 256];
  __syncthreads();
  float acc[8] = {};
  for (int i = 0; i < 512; i += 4) {
    float w0 = g1w[(i + 0) * 256 + t];
    float w1 = g1w[(i + 1) * 256 + t];
    float w2 = g1w[(i + 2) * 256 + t];
    float w3 = g1w[(i + 3) * 256 + t];
#pragma unroll
    for (int r = 0; r < 8; ++r) {
      float4 xv = *(const float4*)&xs[r][i];
      acc[r] += xv.x * w0 + xv.y * w1 + xv.z * w2 + xv.w * w3;
    }
  }
  float b1 = g1b[t], w2_ = g2w[t];
  float p[8];
#pragma unroll
  for (int r = 0; r < 8; ++r) {
    float h = acc[r] + b1;
    h = h > 0.f ? h : 0.f;
    p[r] = h * w2_;
  }
#pragma unroll
  for (int r = 0; r < 8; ++r)
    for (int off = 32; off; off >>= 1) p[r] += __shfl_xor(p[r], off, 64);
  if ((t & 63) == 0) {
#pragma unroll
    for (int r = 0; r < 8; ++r) red[r * 4 + (t >> 6)] = p[r];
  }
  __syncthreads();
  if (t < 8) {
    float s = red[t * 4] + red[t * 4 + 1] + red[t * 4 + 2] + red[t * 4 + 3] + g2b[0];
    gate[r0 + t] = 1.f / (1.f + __expf(-s));
  }
}

// ---------------- gated blend + layernorm ----------------

__global__ __launch_bounds__(256) void blend_ln_kernel(
    const float* __restrict__ o, const float* __restrict__ x,
    const float* __restrict__ gate, const float* __restrict__ ln_g,
    const float* __restrict__ ln_b, float* __restrict__ y) {
  __shared__ float r1[4], r2[4];
  const int row = blockIdx.x, t = threadIdx.x;
  float g = gate[row];
  float2 o2 = *(const float2*)&o[(size_t)row * DD + t * 2];
  float2 x2 = *(const float2*)&x[(size_t)row * DD + t * 2];
  float va = o2.x * g + x2.x * (1.f - g);
  float vb = o2.y * g + x2.y * (1.f - g);
  float s = va + vb, q = va * va + vb * vb;
  for (int off = 32; off; off >>= 1) {
    s += __shfl_xor(s, off, 64);
    q += __shfl_xor(q, off, 64);
  }
  if ((t & 63) == 0) { r1[t >> 6] = s; r2[t >> 6] = q; }
  __syncthreads();
  s = r1[0] + r1[1] + r1[2] + r1[3];
  q = r2[0] + r2[1] + r2[2] + r2[3];
  float mean = s * (1.f / 512.f);
  float var = q * (1.f / 512.f) - mean * mean;
  float rstd = rsqrtf(var + 1e-5f);
  float2 lg = *(const float2*)&ln_g[t * 2];
  float2 lb = *(const float2*)&ln_b[t * 2];
  float2 out;
  out.x = (va - mean) * rstd * lg.x + lb.x;
  out.y = (vb - mean) * rstd * lg.y + lb.y;
  *(float2*)&y[(size_t)row * DD + t * 2] = out;
}

extern "C" void kernel_launch(void* const* d_in, const int* in_sizes, int n_in,
                              void* d_out, int out_size, void* d_ws, size_t ws_size,
                              hipStream_t stream) {
  const float* x   = (const float*)d_in[0];
  const float* wq  = (const float*)d_in[1];
  const float* bq  = (const float*)d_in[2];
  const float* wk  = (const float*)d_in[3];
  const float* bk  = (const float*)d_in[4];
  const float* wv  = (const float*)d_in[5];
  const float* bv  = (const float*)d_in[6];
  const float* wo  = (const float*)d_in[7];
  const float* bo  = (const float*)d_in[8];
  const float* g1w = (const float*)d_in[9];
  const float* g1b = (const float*)d_in[10];
  const float* g2w = (const float*)d_in[11];
  const float* g2b = (const float*)d_in[12];
  const float* lng = (const float*)d_in[13];
  const float* lnb = (const float*)d_in[14];

  float* y    = (float*)d_out;
  float* attn = y + (size_t)Y_SIZE;

  char* ws = (char*)d_ws;
  ushort* xb  = (ushort*)(ws);                       // 4 MB
  ushort* wqt = (ushort*)(ws + (4 << 20));           // 512 KB
  ushort* wkt = (ushort*)(ws + (4 << 20) + (512 << 10));
  ushort* wvt = (ushort*)(ws + (5 << 20));
  ushort* wot = (ushort*)(ws + (5 << 20) + (512 << 10));
  ushort* qb  = (ushort*)(ws + (6 << 20));           // 4 MB
  ushort* kb  = (ushort*)(ws + (10 << 20));          // 4 MB
  ushort* vt  = (ushort*)(ws + (14 << 20));          // 4 MB
  ushort* ctx = (ushort*)(ws + (18 << 20));          // 4 MB
  float*  o   = (float*)(ws + (22 << 20));           // 8 MB
  float*  gate= (float*)(ws + (30 << 20));           // 16 KB

  hipLaunchKernelGGL(conv_x_kernel, dim3(Y_SIZE / 1024), dim3(256), 0, stream, x, xb);
  hipLaunchKernelGGL(conv_wt_kernel, dim3(8, 8, 4), dim3(256), 0, stream,
                     wq, wk, wv, wo, wqt, wkt, wvt, wot);
  hipLaunchKernelGGL(proj_qkv_kernel, dim3(64, 8, 3), dim3(256), 0, stream,
                     xb, wqt, bq, wkt, bk, wvt, bv, qb, kb, vt);
  hipLaunchKernelGGL(gate_kernel, dim3(512), dim3(256), 0, stream,
                     x, g1w, g1b, g2w, g2b, gate);
  hipLaunchKernelGGL(attn_kernel, dim3(64, 16), dim3(256), 0, stream,
                     qb, kb, vt, attn, ctx);
  hipLaunchKernelGGL(proj_o_kernel, dim3(64, 8), dim3(256), 0, stream,
                     ctx, wot, bo, o);
  hipLaunchKernelGGL(blend_ln_kernel, dim3(4096), dim3(256), 0, stream,
                     o, x, gate, lng, lnb, y);
}